// Round 15
// baseline (1309.267 us; speedup 1.0000x reference)
//
#include <hip/hip_runtime.h>
#include <hip/hip_bf16.h>
#include <cfloat>
#include <climits>

#define DDIM 64
#define KSEL 16
#define WINDOW 2048          // T-estimation window
#define NCHUNK 16            // chunks of 128 in window
#define WSL 32               // window slices (seed2)
#define WSLEN 64             // queries per slice
#define SCAP 8               // per-thread append cap (seed2)
#define C1 0.017f            // > 2^-6: covers 2*bf16 dot error via Cauchy-Schwarz
#define C2 0.05f             // covers f32 accumulation + threshold rounding
#define RFAST 1024           // fast-path candidate limit (block recheck)
#define RBUF 1040            // LDS pack slots: fast path <=1024; fallback 16+1024
#define LSLOT 24             // per-(key,block) LDS hit slots (filter, lambda~7.8)

typedef __attribute__((ext_vector_type(8))) short short8;
typedef __attribute__((ext_vector_type(4))) float f32x4;

// ---------------------------------------------------------------------------
// numpy pairwise-sum emulation for n=64 contiguous f32 (validated r3-r14).
// ---------------------------------------------------------------------------
__device__ __forceinline__ float np_sum64(const float* p) {
  float lane[16];
#pragma unroll
  for (int j = 0; j < 16; ++j)
    lane[j] = __fadd_rn(__fadd_rn(p[j], p[16 + j]),
                        __fadd_rn(p[32 + j], p[48 + j]));
  float u[8];
#pragma unroll
  for (int j = 0; j < 8; ++j) u[j] = __fadd_rn(lane[j], lane[j + 8]);
  float w[4];
#pragma unroll
  for (int j = 0; j < 4; ++j) w[j] = __fadd_rn(u[j], u[j + 4]);
  return __fadd_rn(__fadd_rn(w[0], w[2]), __fadd_rn(w[1], w[3]));
}

__device__ __forceinline__ void insert16(float* bd, int* bi, float cd, int ci) {
#pragma unroll
  for (int p = 0; p < KSEL; ++p) {
    bool sm = (cd < bd[p]) || (cd == bd[p] && ci < bi[p]);
    float td = bd[p]; int ti = bi[p];
    bd[p] = sm ? cd : td; bi[p] = sm ? ci : ti;
    cd = sm ? td : cd;   ci = sm ? ti : ci;
  }
}

// Monotone map: lexicographic (d,j) ascending == u64 ascending (j distinct).
__device__ __forceinline__ unsigned long long packdj(float d, int j) {
  unsigned db = __float_as_uint(d);
  db = (db & 0x80000000u) ? ~db : (db | 0x80000000u);
  return ((unsigned long long)db << 32) | (unsigned)j;
}

__device__ __forceinline__ unsigned mapmono(float d) {
  unsigned db = __float_as_uint(d);
  return (db & 0x80000000u) ? ~db : (db | 0x80000000u);
}

__device__ __forceinline__ float unmapmono(unsigned m) {
  return (m & 0x80000000u) ? __uint_as_float(m & 0x7fffffffu)
                           : __uint_as_float(~m);
}

// np-exact d2: sequential fmaf chain (BLAS per-element order), validated r3.
__device__ __forceinline__ float exact_d2(const float* __restrict__ k,
                                          const float* __restrict__ q,
                                          float k2, float q2) {
  float c = 0.f;
#pragma unroll
  for (int t = 0; t < DDIM; ++t) c = fmaf(k[t], q[t], c);
  return __fsub_rn(__fadd_rn(k2, q2), __fmul_rn(2.0f, c));
}

__device__ __forceinline__ unsigned bf2pack(float a, float b) {
  __hip_bfloat16 ha = __float2bfloat16(a), hb = __float2bfloat16(b);
  unsigned short ua = *reinterpret_cast<unsigned short*>(&ha);
  unsigned short ub = *reinterpret_cast<unsigned short*>(&hb);
  return (unsigned)ua | ((unsigned)ub << 16);
}

// ---------------------------------------------------------------------------
// Kernel A: np-exact row norms + bf16 conversion + sqrt norms. Validated.
// ---------------------------------------------------------------------------
__global__ __launch_bounds__(256) void knn_norms_np(
    const float* __restrict__ keys, const float* __restrict__ queries,
    int Nk, int Nq, float* __restrict__ k2, float* __restrict__ q2,
    float* __restrict__ sk, float* __restrict__ sq,
    unsigned short* __restrict__ kbf, unsigned short* __restrict__ qbf) {
  int i = blockIdx.x * 256 + threadIdx.x;
  if (i >= Nk + Nq) return;
  bool isK = i < Nk;
  int r = isK ? i : i - Nk;
  const float4* row4 = reinterpret_cast<const float4*>(
      (isK ? keys : queries) + (size_t)r * DDIM);
  float p[DDIM]; unsigned hw[DDIM / 2];
#pragma unroll
  for (int t = 0; t < 16; ++t) {
    float4 v = row4[t];
    p[4 * t + 0] = __fmul_rn(v.x, v.x);
    p[4 * t + 1] = __fmul_rn(v.y, v.y);
    p[4 * t + 2] = __fmul_rn(v.z, v.z);
    p[4 * t + 3] = __fmul_rn(v.w, v.w);
    hw[2 * t + 0] = bf2pack(v.x, v.y);
    hw[2 * t + 1] = bf2pack(v.z, v.w);
  }
  float s = np_sum64(p);
  uint4* dst = reinterpret_cast<uint4*>((isK ? kbf : qbf) + (size_t)r * DDIM);
#pragma unroll
  for (int t = 0; t < 8; ++t)
    dst[t] = make_uint4(hw[4 * t], hw[4 * t + 1], hw[4 * t + 2], hw[4 * t + 3]);
  if (isK) { k2[r] = s; sk[r] = sqrtf(s); }
  else     { q2[r] = s; sq[r] = sqrtf(s); }
}

// ---------------------------------------------------------------------------
// Kernel B: init cmin = UINT_MAX, cnt = 0.
// ---------------------------------------------------------------------------
__global__ __launch_bounds__(256) void knn_init(
    unsigned* __restrict__ cmin, int nmin, unsigned* __restrict__ cnt, int ncnt) {
  int i = blockIdx.x * 256 + threadIdx.x;
  if (i < nmin) cmin[i] = 0xFFFFFFFFu;
  if (i < ncnt) cnt[i] = 0u;
}

// ---------------------------------------------------------------------------
// Kernel C (chunkmin): MFMA upper-bound chunk minima over window. Validated r8.
// ---------------------------------------------------------------------------
__global__ __launch_bounds__(256) void knn_chunkmin(
    const unsigned short* __restrict__ kbf, const unsigned short* __restrict__ qbf,
    const float* __restrict__ k2a, const float* __restrict__ ska,
    const float* __restrict__ q2a, const float* __restrict__ sqa,
    unsigned* __restrict__ cmin) {
  int tid = threadIdx.x, lane = tid & 63, w = tid >> 6;
  int kb = blockIdx.x & 127;
  int qt = blockIdx.x >> 7;
  int kbase = kb * 64;
  int qbase = qt * 256 + w * 64;
  int chunk = qbase >> 7;
  int l16 = lane & 15, lg = lane >> 4;

  short8 a0[4], a1[4];
#pragma unroll
  for (int s = 0; s < 4; ++s) {
    const short8* krow = reinterpret_cast<const short8*>(
        kbf + (size_t)(kbase + s * 16 + l16) * DDIM);
    a0[s] = krow[lg]; a1[s] = krow[lg + 4];
  }
  float KA[16], KB[16];
#pragma unroll
  for (int s = 0; s < 4; ++s)
#pragma unroll
    for (int r = 0; r < 4; ++r) {
      int kk = kbase + s * 16 + lg * 4 + r;
      KA[s * 4 + r] = k2a[kk] + C2;
      KB[s * 4 + r] = C1 * ska[kk];
    }
  float mreg[16];
#pragma unroll
  for (int i = 0; i < 16; ++i) mreg[i] = FLT_MAX;

#pragma unroll
  for (int qs = 0; qs < 4; ++qs) {
    int q = qbase + qs * 16 + l16;
    const short8* qrow = reinterpret_cast<const short8*>(qbf + (size_t)q * DDIM);
    short8 b0 = qrow[lg], b1 = qrow[lg + 4];
    float q2l = q2a[q], sql = sqa[q];
    f32x4 acc[4];
#pragma unroll
    for (int s = 0; s < 4; ++s) {
      f32x4 z = {0.f, 0.f, 0.f, 0.f};
      z = __builtin_amdgcn_mfma_f32_16x16x32_bf16(a0[s], b0, z, 0, 0, 0);
      z = __builtin_amdgcn_mfma_f32_16x16x32_bf16(a1[s], b1, z, 0, 0, 0);
      acc[s] = z;
    }
#pragma unroll
    for (int s = 0; s < 4; ++s)
#pragma unroll
      for (int r = 0; r < 4; ++r) {
        int i = s * 4 + r;
        float u = fmaf(KB[i], sql, KA[i] + q2l) - 2.0f * acc[s][r];
        mreg[i] = fminf(mreg[i], u);
      }
  }
#pragma unroll
  for (int m = 1; m < 16; m <<= 1)
#pragma unroll
    for (int i = 0; i < 16; ++i)
      mreg[i] = fminf(mreg[i], __shfl_xor(mreg[i], m));
  if (l16 == 0) {
#pragma unroll
    for (int i = 0; i < 16; ++i) {
      int kk = kbase + (i >> 2) * 16 + lg * 4 + (i & 3);
      atomicMin(&cmin[(size_t)kk * NCHUNK + chunk], mapmono(mreg[i]));
    }
  }
}

// ---------------------------------------------------------------------------
// Kernel D (trough): T_rough[key] = max over 16 chunk minima. Validated r8.
// ---------------------------------------------------------------------------
__global__ __launch_bounds__(256) void knn_trough(
    const unsigned* __restrict__ cmin, float* __restrict__ PR, int Nk) {
  int k = blockIdx.x * 256 + threadIdx.x;
  if (k >= Nk) return;
  unsigned m = 0;
#pragma unroll
  for (int c = 0; c < NCHUNK; ++c) {
    unsigned v = cmin[(size_t)k * NCHUNK + c];
    m = v > m ? v : m;
  }
  PR[k] = unmapmono(m);
}

// ---------------------------------------------------------------------------
// Kernel E (seed2): np-exact d2 over window, cheap append <= T_rough.
// Validated r8-r14 (SCAP = 8).
// ---------------------------------------------------------------------------
__global__ __launch_bounds__(256) void knn_seed2(
    const float* __restrict__ keys, const float* __restrict__ queries,
    const float* __restrict__ k2a, const float* __restrict__ q2a,
    const float* __restrict__ PR, unsigned long long* __restrict__ spack) {
  __shared__ unsigned long long lbuf[256 * SCAP];
  int tid = threadIdx.x;
  int kb = blockIdx.x & 31, sl = blockIdx.x >> 5;
  int key = kb * 256 + tid;

  float4 kreg[16];
  const float4* kp = reinterpret_cast<const float4*>(keys + (size_t)key * DDIM);
#pragma unroll
  for (int t = 0; t < 16; ++t) kreg[t] = kp[t];
  float myk2 = k2a[key], pr = PR[key];
  int cnt = 0;

  int j0 = sl * WSLEN;
  for (int j = j0; j < j0 + WSLEN; j += 4) {
    const float4* q40 = reinterpret_cast<const float4*>(queries + (size_t)(j + 0) * DDIM);
    const float4* q41 = reinterpret_cast<const float4*>(queries + (size_t)(j + 1) * DDIM);
    const float4* q42 = reinterpret_cast<const float4*>(queries + (size_t)(j + 2) * DDIM);
    const float4* q43 = reinterpret_cast<const float4*>(queries + (size_t)(j + 3) * DDIM);
    float c0 = 0.f, c1 = 0.f, c2 = 0.f, c3 = 0.f;
#pragma unroll
    for (int t = 0; t < 16; ++t) {
      float4 a0 = q40[t], a1 = q41[t], a2 = q42[t], a3 = q43[t];
      float k0 = kreg[t].x, k1 = kreg[t].y, k2v = kreg[t].z, k3 = kreg[t].w;
      c0 = fmaf(k0, a0.x, c0); c1 = fmaf(k0, a1.x, c1);
      c2 = fmaf(k0, a2.x, c2); c3 = fmaf(k0, a3.x, c3);
      c0 = fmaf(k1, a0.y, c0); c1 = fmaf(k1, a1.y, c1);
      c2 = fmaf(k1, a2.y, c2); c3 = fmaf(k1, a3.y, c3);
      c0 = fmaf(k2v, a0.z, c0); c1 = fmaf(k2v, a1.z, c1);
      c2 = fmaf(k2v, a2.z, c2); c3 = fmaf(k2v, a3.z, c3);
      c0 = fmaf(k3, a0.w, c0); c1 = fmaf(k3, a1.w, c1);
      c2 = fmaf(k3, a2.w, c2); c3 = fmaf(k3, a3.w, c3);
    }
    float dots[4] = {c0, c1, c2, c3};
#pragma unroll
    for (int u = 0; u < 4; ++u) {
      float d2 = __fsub_rn(__fadd_rn(myk2, q2a[j + u]),
                           __fmul_rn(2.0f, dots[u]));
      if (d2 <= pr) {
        lbuf[tid * SCAP + (cnt < SCAP ? cnt : SCAP - 1)] = packdj(d2, j + u);
        cnt++;
      }
    }
  }
  int wn = cnt < SCAP ? cnt : SCAP;
  unsigned long long* dst =
      spack + ((size_t)(kb * WSL + sl) * 256 + tid) * SCAP;
#pragma unroll
  for (int e = 0; e < SCAP; ++e)
    dst[e] = (e < wn) ? lbuf[tid * SCAP + e] : ~0ull;
}

// ---------------------------------------------------------------------------
// Kernel F (thresh2): wave-per-key rank-count over 256 appended packs -> T.
// PS stores PRE-HALVED constants (r13-validated).
// ---------------------------------------------------------------------------
__global__ __launch_bounds__(256) void knn_thresh2(
    const unsigned long long* __restrict__ spack, const float* __restrict__ PR,
    const float* __restrict__ k2a, const float* __restrict__ ska,
    float2* __restrict__ PS) {
  __shared__ unsigned long long packs[4][WSL * SCAP];
  __shared__ float Tsh[4];
  int tid = threadIdx.x, w = tid >> 6, lane = tid & 63;
  int key = blockIdx.x * 4 + w;
  int kb = key >> 8, t = key & 255;

  unsigned long long mine[4];
#pragma unroll
  for (int r = 0; r < 4; ++r) {
    int e = lane + 64 * r;
    int sl = e >> 3, p = e & 7;
    mine[r] = spack[((size_t)(kb * WSL + sl) * 256 + t) * SCAP + p];
    packs[w][e] = mine[r];
  }
  if (lane == 0) Tsh[w] = PR[key];
  __syncthreads();
  int c0 = 0, c1 = 0, c2 = 0, c3 = 0;
  for (int m = 0; m < WSL * SCAP; ++m) {
    unsigned long long pm = packs[w][m];
    c0 += pm < mine[0]; c1 += pm < mine[1];
    c2 += pm < mine[2]; c3 += pm < mine[3];
  }
  int c[4] = {c0, c1, c2, c3};
  __syncthreads();
#pragma unroll
  for (int r = 0; r < 4; ++r)
    if (c[r] == KSEL - 1 && mine[r] != ~0ull)
      Tsh[w] = unmapmono((unsigned)(mine[r] >> 32));
  __syncthreads();
  if (lane == 0) {
    float T = Tsh[w];
    PS[key] = make_float2(0.5f * (k2a[key] - T - C2), -0.5f * C1 * ska[key]);
  }
}

// ---------------------------------------------------------------------------
// Kernel G (MFMA filter v5): block = 4 waves, each wave owns a DIFFERENT
// 64-key strip (Tk = 256/block); all 4 waves sweep the SAME 1024-query tile
// in lockstep (__syncthreads every 64 queries) so waves 2-4 hit the shared
// CU L1 on the query-row loads -> per-CU query traffic /4 (570 -> 139 MB
// total). MFMA fragments, threshold math, LDS hit aggregation and flush
// byte-identical to r13/r14; hit lists now 256 keys x LSLOT=24.
// ---------------------------------------------------------------------------
__global__ __launch_bounds__(256) void knn_filter(
    const unsigned short* __restrict__ kbf, const unsigned short* __restrict__ qbf,
    const float* __restrict__ q2a, const float* __restrict__ sqa,
    const float2* __restrict__ PS,
    unsigned* __restrict__ cnt, unsigned short* __restrict__ cbuf, int CAP) {
  __shared__ int lcnt[256];
  __shared__ int lbase[256];
  __shared__ unsigned short lhit[256 * LSLOT];   // 12 KB
  int tid = threadIdx.x;
  int lane = tid & 63, w = tid >> 6;
  int kb = blockIdx.x & 31;              // 32 key-strips of 256
  int qt = blockIdx.x >> 5;              // 0..31
  int kbase = kb * 256 + w * 64;         // per-wave 64 keys
  int qblk = qt * 1024;
  int l16 = lane & 15, lg = lane >> 4;

  lcnt[tid] = 0;
  __syncthreads();

  short8 a0[4], a1[4];
#pragma unroll
  for (int s = 0; s < 4; ++s) {
    const short8* krow = reinterpret_cast<const short8*>(
        kbf + (size_t)(kbase + s * 16 + l16) * DDIM);
    a0[s] = krow[lg]; a1[s] = krow[lg + 4];
  }
  float psA[16], psB[16];
#pragma unroll
  for (int s = 0; s < 4; ++s)
#pragma unroll
    for (int r = 0; r < 4; ++r) {
      float2 ps = PS[kbase + s * 16 + lg * 4 + r];
      psA[s * 4 + r] = ps.x; psB[s * 4 + r] = ps.y;
    }

  for (int qo = 0; qo < 16; ++qo) {      // 16 lockstep steps of 64 queries
    int qbase = qblk + qo * 64;
#pragma unroll
    for (int qs = 0; qs < 4; ++qs) {
      int q = qbase + qs * 16 + l16;
      const short8* qrow = reinterpret_cast<const short8*>(qbf + (size_t)q * DDIM);
      short8 b0 = qrow[lg], b1 = qrow[lg + 4];
      float q2l = q2a[q], sql = sqa[q];
      float h = 0.5f * q2l;

      f32x4 acc[4];
#pragma unroll
      for (int s = 0; s < 4; ++s) {
        f32x4 z = {0.f, 0.f, 0.f, 0.f};
        z = __builtin_amdgcn_mfma_f32_16x16x32_bf16(a0[s], b0, z, 0, 0, 0);
        z = __builtin_amdgcn_mfma_f32_16x16x32_bf16(a1[s], b1, z, 0, 0, 0);
        acc[s] = z;
      }
      unsigned m = 0;
#pragma unroll
      for (int s = 0; s < 4; ++s)
#pragma unroll
        for (int r = 0; r < 4; ++r) {
          int i = s * 4 + r;
          float thr = fmaf(psB[i], sql, psA[i] + h);
          m |= (acc[s][r] > thr) ? (1u << i) : 0u;
        }
      while (m) {
        int b = __ffs(m) - 1; m &= m - 1;
        int kl = w * 64 + (b >> 2) * 16 + lg * 4 + (b & 3);
        int slot = atomicAdd(&lcnt[kl], 1);
        if (slot < LSLOT) lhit[kl * LSLOT + slot] = (unsigned short)q;
      }
    }
    __syncthreads();                     // bound wave drift for L1 sharing
  }
  // flush: thread tid owns block-local key tid
  {
    int lc = lcnt[tid];
    int key = kb * 256 + tid;
    unsigned add = (lc > LSLOT) ? (unsigned)(CAP + 1000) : (unsigned)lc;
    lbase[tid] = (lc > 0) ? (int)atomicAdd(&cnt[key], add) : 0;
    lcnt[tid] = lc < LSLOT ? lc : LSLOT;
  }
  __syncthreads();
  for (int idx = tid; idx < 256 * LSLOT; idx += 256) {
    int kl = idx / LSLOT, sl = idx - kl * LSLOT;
    if (sl < lcnt[kl]) {
      int pos = lbase[kl] + sl;
      if (pos < CAP)
        cbuf[(size_t)(kb * 256 + kl) * CAP + pos] = lhit[kl * LSLOT + sl];
    }
  }
}

// ---------------------------------------------------------------------------
// Kernel H (recheck v6, r14): block-per-key, 4 lanes per candidate with
// bit-exact segment-handoff chain. Selection rank-count; chunked full-scan
// fallback. Unchanged from r14 (measured 152 us).
// ---------------------------------------------------------------------------
__global__ __launch_bounds__(256) void knn_recheck(
    const float* __restrict__ keys, const float* __restrict__ queries,
    const float* __restrict__ k2a, const float* __restrict__ q2a,
    const unsigned* __restrict__ cnt, const unsigned short* __restrict__ cbuf,
    int CAP, int Nq, float* __restrict__ outIdx) {
  __shared__ unsigned long long packs[RBUF];       // 8.3 KB
  __shared__ unsigned long long cur16[KSEL];
  __shared__ float4 klds[16];
  int tid = threadIdx.x;
  int key = blockIdx.x;
  float myk2 = k2a[key];

  if (tid < 16)
    klds[tid] = reinterpret_cast<const float4*>(keys + (size_t)key * DDIM)[tid];
  __syncthreads();

  unsigned n = cnt[key];
  unsigned lim = (unsigned)((CAP < RFAST) ? CAP : RFAST);
  if (n <= lim) {
    const unsigned short* mc = cbuf + (size_t)key * CAP;
    int sub = tid & 3;
    int lanebase = (tid & 63) & ~3;
    for (unsigned base = 0; base < n; base += 64) {
      unsigned e = base + (unsigned)(tid >> 2);
      unsigned ec = (e < n) ? e : (n - 1);
      int j = mc[ec];
      const float4* Q = reinterpret_cast<const float4*>(queries + (size_t)j * DDIM);
      float4 rr[4];
      rr[0] = Q[sub];
      rr[1] = Q[sub + 4];
      rr[2] = Q[sub + 8];
      rr[3] = Q[sub + 12];
      float q2j = q2a[j];
      float c = 0.f;
#pragma unroll
      for (int seg = 0; seg < 16; ++seg) {
        float4 kk = klds[seg];
        float4 qq = rr[seg >> 2];
        float t = c;
        t = fmaf(kk.x, qq.x, t);
        t = fmaf(kk.y, qq.y, t);
        t = fmaf(kk.z, qq.z, t);
        t = fmaf(kk.w, qq.w, t);
        c = __shfl(t, lanebase + (seg & 3), 64);
      }
      if (e < n && sub == 0) {
        float d2 = __fsub_rn(__fadd_rn(myk2, q2j), __fmul_rn(2.0f, c));
        packs[e] = packdj(d2, j);
      }
    }
    __syncthreads();
    int N = (int)n;
    for (int i = tid; i < N; i += 256) {
      unsigned long long mp = packs[i];
      int c = 0;
      for (int m = 0; m < N; ++m) c += packs[m] < mp;
      if (c < KSEL)
        outIdx[(size_t)key * KSEL + c] = (float)(int)(mp & 0xFFFFFFFFull);
    }
    return;
  }

  // ---- fallback: exact full scan (correctness net, expected never) ----
  float bd[KSEL]; int bi[KSEL];
#pragma unroll
  for (int p = 0; p < KSEL; ++p) { bd[p] = FLT_MAX; bi[p] = INT_MAX; }
  const float* krow = keys + (size_t)key * DDIM;
  for (int j = tid; j < Nq; j += 256) {
    float d2 = exact_d2(krow, queries + (size_t)j * DDIM, myk2, q2a[j]);
    if (d2 < bd[KSEL - 1] || (d2 == bd[KSEL - 1] && j < bi[KSEL - 1]))
      insert16(bd, bi, d2, j);
  }
  if (tid < KSEL) cur16[tid] = ~0ull;
  __syncthreads();
  for (int r = 0; r < 4; ++r) {
    if ((tid >> 6) == r) {
#pragma unroll
      for (int p = 0; p < KSEL; ++p)
        packs[KSEL + (tid & 63) * KSEL + p] = packdj(bd[p], bi[p]);
    }
    if (tid < KSEL) packs[tid] = cur16[tid];
    __syncthreads();
    const int N = KSEL + 64 * KSEL;   // 1040
    for (int i = tid; i < N; i += 256) {
      unsigned long long mp = packs[i];
      int c = 0;
      for (int m = 0; m < N; ++m) c += packs[m] < mp;
      if (c < KSEL) cur16[c] = mp;
    }
    __syncthreads();
  }
  if (tid < KSEL)
    outIdx[(size_t)key * KSEL + tid] =
        (float)(int)(cur16[tid] & 0xFFFFFFFFull);
}

// ---------------------------------------------------------------------------
// Kernel I: recompute distances sum((k-q)^2) in f64, emit f32 (validated).
// ---------------------------------------------------------------------------
__global__ __launch_bounds__(256) void knn_dist_d(
    const float* __restrict__ keys, const float* __restrict__ queries,
    const float* __restrict__ outIdx, int Nk, float* __restrict__ outDist) {
  int e = blockIdx.x * 256 + threadIdx.x;
  if (e >= Nk * KSEL) return;
  int key = e >> 4;
  int id = (int)outIdx[e];
  const float* kp = keys + (size_t)key * DDIM;
  const float* qp = queries + (size_t)id * DDIM;
  double s = 0.0;
#pragma unroll
  for (int t = 0; t < DDIM; ++t) {
    double d = (double)kp[t] - (double)qp[t];
    s = fma(d, d, s);
  }
  outDist[e] = (float)s;
}

// ---------------------------------------------------------------------------
extern "C" void kernel_launch(void* const* d_in, const int* in_sizes, int n_in,
                              void* d_out, int out_size, void* d_ws, size_t ws_size,
                              hipStream_t stream) {
  const float* keys    = (const float*)d_in[0];
  const float* queries = (const float*)d_in[1];
  int Nk = in_sizes[0] / DDIM;   // 8192
  int Nq = in_sizes[1] / DDIM;   // 32768
  float* out = (float*)d_out;

  char* wp = (char*)d_ws;
  unsigned long long* spack = (unsigned long long*)wp;
  wp += (size_t)Nk * WSL * SCAP * 8;                       // 16.78 MB
  float*    k2  = (float*)wp;  wp += (size_t)Nk * 4;
  float*    q2  = (float*)wp;  wp += (size_t)Nq * 4;
  float*    sk  = (float*)wp;  wp += (size_t)Nk * 4;
  float*    sq  = (float*)wp;  wp += (size_t)Nq * 4;
  float*    PR  = (float*)wp;  wp += (size_t)Nk * 4;
  float2*   PS  = (float2*)wp; wp += (size_t)Nk * 8;
  unsigned* cnt = (unsigned*)wp; wp += (size_t)Nk * 4;
  unsigned* cmin = (unsigned*)wp; wp += (size_t)Nk * NCHUNK * 4;
  unsigned short* kbf = (unsigned short*)wp; wp += (size_t)Nk * DDIM * 2;
  unsigned short* qbf = (unsigned short*)wp; wp += (size_t)Nq * DDIM * 2;
  size_t fixedBytes = (size_t)(wp - (char*)d_ws);
  unsigned short* cbuf = (unsigned short*)wp;
  long long rem = (long long)ws_size - (long long)fixedBytes;
  int CAP = (int)(rem / (2 * (long long)Nk));
  if (CAP > 2048) CAP = 2048;
  if (CAP < 16) CAP = 16;

  int nInit = Nk * NCHUNK;
  knn_init<<<(nInit + 255) / 256, 256, 0, stream>>>(cmin, nInit, cnt, Nk);
  knn_norms_np<<<(Nk + Nq + 255) / 256, 256, 0, stream>>>(
      keys, queries, Nk, Nq, k2, q2, sk, sq, kbf, qbf);
  knn_chunkmin<<<128 * (WINDOW / 256), 256, 0, stream>>>(
      kbf, qbf, k2, sk, q2, sq, cmin);
  knn_trough<<<(Nk + 255) / 256, 256, 0, stream>>>(cmin, PR, Nk);
  knn_seed2<<<32 * WSL, 256, 0, stream>>>(keys, queries, k2, q2, PR, spack);
  knn_thresh2<<<Nk / 4, 256, 0, stream>>>(spack, PR, k2, sk, PS);
  knn_filter<<<(Nk / 256) * (Nq / 1024), 256, 0, stream>>>(
      kbf, qbf, q2, sq, PS, cnt, cbuf, CAP);
  knn_recheck<<<Nk, 256, 0, stream>>>(
      keys, queries, k2, q2, cnt, cbuf, CAP, Nq, out);
  knn_dist_d<<<(Nk * KSEL + 255) / 256, 256, 0, stream>>>(
      keys, queries, out, Nk, out + (size_t)Nk * KSEL);
}

// Round 16
// 377.911 us; speedup vs baseline: 3.4645x; 3.4645x over previous
//
#include <hip/hip_runtime.h>
#include <hip/hip_bf16.h>
#include <cfloat>
#include <climits>

#define DDIM 64
#define KSEL 16
#define WINDOW 4096          // T-estimation window (r16: 2048 -> 4096)
#define NCHUNK 32            // chunks of 128 in window
#define WSL 64               // window slices (seed2)
#define WSLEN 64             // queries per slice
#define SCAP 4               // per-thread append cap (seed2; lambda~0.75)
#define C1 0.017f            // > 2^-6: covers 2*bf16 dot error via Cauchy-Schwarz
#define C2 0.05f             // covers f32 accumulation + threshold rounding
#define RFAST 1024           // fast-path candidate limit (block recheck)
#define RBUF 1040            // LDS pack slots: fast path <=1024; fallback 16+1024
#define LSLOT 32             // per-(key,block) LDS hit slots (filter; r15's 24 overflowed)

typedef __attribute__((ext_vector_type(8))) short short8;
typedef __attribute__((ext_vector_type(4))) float f32x4;

// ---------------------------------------------------------------------------
// numpy pairwise-sum emulation for n=64 contiguous f32 (validated r3-r14).
// ---------------------------------------------------------------------------
__device__ __forceinline__ float np_sum64(const float* p) {
  float lane[16];
#pragma unroll
  for (int j = 0; j < 16; ++j)
    lane[j] = __fadd_rn(__fadd_rn(p[j], p[16 + j]),
                        __fadd_rn(p[32 + j], p[48 + j]));
  float u[8];
#pragma unroll
  for (int j = 0; j < 8; ++j) u[j] = __fadd_rn(lane[j], lane[j + 8]);
  float w[4];
#pragma unroll
  for (int j = 0; j < 4; ++j) w[j] = __fadd_rn(u[j], u[j + 4]);
  return __fadd_rn(__fadd_rn(w[0], w[2]), __fadd_rn(w[1], w[3]));
}

__device__ __forceinline__ void insert16(float* bd, int* bi, float cd, int ci) {
#pragma unroll
  for (int p = 0; p < KSEL; ++p) {
    bool sm = (cd < bd[p]) || (cd == bd[p] && ci < bi[p]);
    float td = bd[p]; int ti = bi[p];
    bd[p] = sm ? cd : td; bi[p] = sm ? ci : ti;
    cd = sm ? td : cd;   ci = sm ? ti : ci;
  }
}

// Monotone map: lexicographic (d,j) ascending == u64 ascending (j distinct).
__device__ __forceinline__ unsigned long long packdj(float d, int j) {
  unsigned db = __float_as_uint(d);
  db = (db & 0x80000000u) ? ~db : (db | 0x80000000u);
  return ((unsigned long long)db << 32) | (unsigned)j;
}

__device__ __forceinline__ unsigned mapmono(float d) {
  unsigned db = __float_as_uint(d);
  return (db & 0x80000000u) ? ~db : (db | 0x80000000u);
}

__device__ __forceinline__ float unmapmono(unsigned m) {
  return (m & 0x80000000u) ? __uint_as_float(m & 0x7fffffffu)
                           : __uint_as_float(~m);
}

// np-exact d2: sequential fmaf chain (BLAS per-element order), validated r3.
__device__ __forceinline__ float exact_d2(const float* __restrict__ k,
                                          const float* __restrict__ q,
                                          float k2, float q2) {
  float c = 0.f;
#pragma unroll
  for (int t = 0; t < DDIM; ++t) c = fmaf(k[t], q[t], c);
  return __fsub_rn(__fadd_rn(k2, q2), __fmul_rn(2.0f, c));
}

__device__ __forceinline__ unsigned bf2pack(float a, float b) {
  __hip_bfloat16 ha = __float2bfloat16(a), hb = __float2bfloat16(b);
  unsigned short ua = *reinterpret_cast<unsigned short*>(&ha);
  unsigned short ub = *reinterpret_cast<unsigned short*>(&hb);
  return (unsigned)ua | ((unsigned)ub << 16);
}

// ---------------------------------------------------------------------------
// Kernel A: np-exact row norms + bf16 conversion + sqrt norms. Validated.
// ---------------------------------------------------------------------------
__global__ __launch_bounds__(256) void knn_norms_np(
    const float* __restrict__ keys, const float* __restrict__ queries,
    int Nk, int Nq, float* __restrict__ k2, float* __restrict__ q2,
    float* __restrict__ sk, float* __restrict__ sq,
    unsigned short* __restrict__ kbf, unsigned short* __restrict__ qbf) {
  int i = blockIdx.x * 256 + threadIdx.x;
  if (i >= Nk + Nq) return;
  bool isK = i < Nk;
  int r = isK ? i : i - Nk;
  const float4* row4 = reinterpret_cast<const float4*>(
      (isK ? keys : queries) + (size_t)r * DDIM);
  float p[DDIM]; unsigned hw[DDIM / 2];
#pragma unroll
  for (int t = 0; t < 16; ++t) {
    float4 v = row4[t];
    p[4 * t + 0] = __fmul_rn(v.x, v.x);
    p[4 * t + 1] = __fmul_rn(v.y, v.y);
    p[4 * t + 2] = __fmul_rn(v.z, v.z);
    p[4 * t + 3] = __fmul_rn(v.w, v.w);
    hw[2 * t + 0] = bf2pack(v.x, v.y);
    hw[2 * t + 1] = bf2pack(v.z, v.w);
  }
  float s = np_sum64(p);
  uint4* dst = reinterpret_cast<uint4*>((isK ? kbf : qbf) + (size_t)r * DDIM);
#pragma unroll
  for (int t = 0; t < 8; ++t)
    dst[t] = make_uint4(hw[4 * t], hw[4 * t + 1], hw[4 * t + 2], hw[4 * t + 3]);
  if (isK) { k2[r] = s; sk[r] = sqrtf(s); }
  else     { q2[r] = s; sq[r] = sqrtf(s); }
}

// ---------------------------------------------------------------------------
// Kernel B: init cmin = UINT_MAX, cnt = 0.
// ---------------------------------------------------------------------------
__global__ __launch_bounds__(256) void knn_init(
    unsigned* __restrict__ cmin, int nmin, unsigned* __restrict__ cnt, int ncnt) {
  int i = blockIdx.x * 256 + threadIdx.x;
  if (i < nmin) cmin[i] = 0xFFFFFFFFu;
  if (i < ncnt) cnt[i] = 0u;
}

// ---------------------------------------------------------------------------
// Kernel C (chunkmin): MFMA upper-bound chunk minima over window. Validated r8.
// ---------------------------------------------------------------------------
__global__ __launch_bounds__(256) void knn_chunkmin(
    const unsigned short* __restrict__ kbf, const unsigned short* __restrict__ qbf,
    const float* __restrict__ k2a, const float* __restrict__ ska,
    const float* __restrict__ q2a, const float* __restrict__ sqa,
    unsigned* __restrict__ cmin) {
  int tid = threadIdx.x, lane = tid & 63, w = tid >> 6;
  int kb = blockIdx.x & 127;
  int qt = blockIdx.x >> 7;              // 0..15 (window/256)
  int kbase = kb * 64;
  int qbase = qt * 256 + w * 64;
  int chunk = qbase >> 7;                // 0..31
  int l16 = lane & 15, lg = lane >> 4;

  short8 a0[4], a1[4];
#pragma unroll
  for (int s = 0; s < 4; ++s) {
    const short8* krow = reinterpret_cast<const short8*>(
        kbf + (size_t)(kbase + s * 16 + l16) * DDIM);
    a0[s] = krow[lg]; a1[s] = krow[lg + 4];
  }
  float KA[16], KB[16];
#pragma unroll
  for (int s = 0; s < 4; ++s)
#pragma unroll
    for (int r = 0; r < 4; ++r) {
      int kk = kbase + s * 16 + lg * 4 + r;
      KA[s * 4 + r] = k2a[kk] + C2;
      KB[s * 4 + r] = C1 * ska[kk];
    }
  float mreg[16];
#pragma unroll
  for (int i = 0; i < 16; ++i) mreg[i] = FLT_MAX;

#pragma unroll
  for (int qs = 0; qs < 4; ++qs) {
    int q = qbase + qs * 16 + l16;
    const short8* qrow = reinterpret_cast<const short8*>(qbf + (size_t)q * DDIM);
    short8 b0 = qrow[lg], b1 = qrow[lg + 4];
    float q2l = q2a[q], sql = sqa[q];
    f32x4 acc[4];
#pragma unroll
    for (int s = 0; s < 4; ++s) {
      f32x4 z = {0.f, 0.f, 0.f, 0.f};
      z = __builtin_amdgcn_mfma_f32_16x16x32_bf16(a0[s], b0, z, 0, 0, 0);
      z = __builtin_amdgcn_mfma_f32_16x16x32_bf16(a1[s], b1, z, 0, 0, 0);
      acc[s] = z;
    }
#pragma unroll
    for (int s = 0; s < 4; ++s)
#pragma unroll
      for (int r = 0; r < 4; ++r) {
        int i = s * 4 + r;
        float u = fmaf(KB[i], sql, KA[i] + q2l) - 2.0f * acc[s][r];
        mreg[i] = fminf(mreg[i], u);
      }
  }
#pragma unroll
  for (int m = 1; m < 16; m <<= 1)
#pragma unroll
    for (int i = 0; i < 16; ++i)
      mreg[i] = fminf(mreg[i], __shfl_xor(mreg[i], m));
  if (l16 == 0) {
#pragma unroll
    for (int i = 0; i < 16; ++i) {
      int kk = kbase + (i >> 2) * 16 + lg * 4 + (i & 3);
      atomicMin(&cmin[(size_t)kk * NCHUNK + chunk], mapmono(mreg[i]));
    }
  }
}

// ---------------------------------------------------------------------------
// Kernel D (trough): T_rough[key] = max over 32 chunk minima. Validated r8.
// ---------------------------------------------------------------------------
__global__ __launch_bounds__(256) void knn_trough(
    const unsigned* __restrict__ cmin, float* __restrict__ PR, int Nk) {
  int k = blockIdx.x * 256 + threadIdx.x;
  if (k >= Nk) return;
  unsigned m = 0;
#pragma unroll
  for (int c = 0; c < NCHUNK; ++c) {
    unsigned v = cmin[(size_t)k * NCHUNK + c];
    m = v > m ? v : m;
  }
  PR[k] = unmapmono(m);
}

// ---------------------------------------------------------------------------
// Kernel E (seed2): np-exact d2 over window, cheap append <= T_rough.
// Validated r8-r14 structure; SCAP=4 (per-thread lambda~0.75; truncation
// only loosens T, never incorrect).
// ---------------------------------------------------------------------------
__global__ __launch_bounds__(256) void knn_seed2(
    const float* __restrict__ keys, const float* __restrict__ queries,
    const float* __restrict__ k2a, const float* __restrict__ q2a,
    const float* __restrict__ PR, unsigned long long* __restrict__ spack) {
  __shared__ unsigned long long lbuf[256 * SCAP];
  int tid = threadIdx.x;
  int kb = blockIdx.x & 31, sl = blockIdx.x >> 5;   // 32 kb x WSL slices
  int key = kb * 256 + tid;

  float4 kreg[16];
  const float4* kp = reinterpret_cast<const float4*>(keys + (size_t)key * DDIM);
#pragma unroll
  for (int t = 0; t < 16; ++t) kreg[t] = kp[t];
  float myk2 = k2a[key], pr = PR[key];
  int cnt = 0;

  int j0 = sl * WSLEN;
  for (int j = j0; j < j0 + WSLEN; j += 4) {
    const float4* q40 = reinterpret_cast<const float4*>(queries + (size_t)(j + 0) * DDIM);
    const float4* q41 = reinterpret_cast<const float4*>(queries + (size_t)(j + 1) * DDIM);
    const float4* q42 = reinterpret_cast<const float4*>(queries + (size_t)(j + 2) * DDIM);
    const float4* q43 = reinterpret_cast<const float4*>(queries + (size_t)(j + 3) * DDIM);
    float c0 = 0.f, c1 = 0.f, c2 = 0.f, c3 = 0.f;
#pragma unroll
    for (int t = 0; t < 16; ++t) {
      float4 a0 = q40[t], a1 = q41[t], a2 = q42[t], a3 = q43[t];
      float k0 = kreg[t].x, k1 = kreg[t].y, k2v = kreg[t].z, k3 = kreg[t].w;
      c0 = fmaf(k0, a0.x, c0); c1 = fmaf(k0, a1.x, c1);
      c2 = fmaf(k0, a2.x, c2); c3 = fmaf(k0, a3.x, c3);
      c0 = fmaf(k1, a0.y, c0); c1 = fmaf(k1, a1.y, c1);
      c2 = fmaf(k1, a2.y, c2); c3 = fmaf(k1, a3.y, c3);
      c0 = fmaf(k2v, a0.z, c0); c1 = fmaf(k2v, a1.z, c1);
      c2 = fmaf(k2v, a2.z, c2); c3 = fmaf(k2v, a3.z, c3);
      c0 = fmaf(k3, a0.w, c0); c1 = fmaf(k3, a1.w, c1);
      c2 = fmaf(k3, a2.w, c2); c3 = fmaf(k3, a3.w, c3);
    }
    float dots[4] = {c0, c1, c2, c3};
#pragma unroll
    for (int u = 0; u < 4; ++u) {
      float d2 = __fsub_rn(__fadd_rn(myk2, q2a[j + u]),
                           __fmul_rn(2.0f, dots[u]));
      if (d2 <= pr) {
        lbuf[tid * SCAP + (cnt < SCAP ? cnt : SCAP - 1)] = packdj(d2, j + u);
        cnt++;
      }
    }
  }
  int wn = cnt < SCAP ? cnt : SCAP;
  unsigned long long* dst =
      spack + ((size_t)(kb * WSL + sl) * 256 + tid) * SCAP;
#pragma unroll
  for (int e = 0; e < SCAP; ++e)
    dst[e] = (e < wn) ? lbuf[tid * SCAP + e] : ~0ull;
}

// ---------------------------------------------------------------------------
// Kernel F (thresh2): wave-per-key rank-count over WSL*SCAP = 256 appended
// packs -> T (16th-smallest of window subset; valid upper bound on global
// 16th). PS stores PRE-HALVED constants (r13-validated).
// ---------------------------------------------------------------------------
__global__ __launch_bounds__(256) void knn_thresh2(
    const unsigned long long* __restrict__ spack, const float* __restrict__ PR,
    const float* __restrict__ k2a, const float* __restrict__ ska,
    float2* __restrict__ PS) {
  __shared__ unsigned long long packs[4][WSL * SCAP];   // 256/key
  __shared__ float Tsh[4];
  int tid = threadIdx.x, w = tid >> 6, lane = tid & 63;
  int key = blockIdx.x * 4 + w;
  int kb = key >> 8, t = key & 255;

  unsigned long long mine[4];
#pragma unroll
  for (int r = 0; r < 4; ++r) {
    int e = lane + 64 * r;                 // 0..255
    int sl = e >> 2, p = e & 3;            // WSL=64 slices x SCAP=4
    mine[r] = spack[((size_t)(kb * WSL + sl) * 256 + t) * SCAP + p];
    packs[w][e] = mine[r];
  }
  if (lane == 0) Tsh[w] = PR[key];
  __syncthreads();
  int c0 = 0, c1 = 0, c2 = 0, c3 = 0;
  for (int m = 0; m < WSL * SCAP; ++m) {
    unsigned long long pm = packs[w][m];
    c0 += pm < mine[0]; c1 += pm < mine[1];
    c2 += pm < mine[2]; c3 += pm < mine[3];
  }
  int c[4] = {c0, c1, c2, c3};
  __syncthreads();
#pragma unroll
  for (int r = 0; r < 4; ++r)
    if (c[r] == KSEL - 1 && mine[r] != ~0ull)
      Tsh[w] = unmapmono((unsigned)(mine[r] >> 32));
  __syncthreads();
  if (lane == 0) {
    float T = Tsh[w];
    PS[key] = make_float2(0.5f * (k2a[key] - T - C2), -0.5f * C1 * ska[key]);
  }
}

// ---------------------------------------------------------------------------
// Kernel G (MFMA filter v3, r13/r14-proven): block = 4 waves x same 64 keys
// x 1024 queries, LDS hit aggregation (LSLOT=32) + single global atomic per
// (key,block); pre-halved threshold epilogue.
// ---------------------------------------------------------------------------
__global__ __launch_bounds__(256) void knn_filter(
    const unsigned short* __restrict__ kbf, const unsigned short* __restrict__ qbf,
    const float* __restrict__ q2a, const float* __restrict__ sqa,
    const float2* __restrict__ PS,
    unsigned* __restrict__ cnt, unsigned short* __restrict__ cbuf, int CAP) {
  __shared__ int lcnt[64];
  __shared__ int lbase[64];
  __shared__ unsigned short lhit[64 * LSLOT];
  int tid = threadIdx.x;
  int lane = tid & 63, w = tid >> 6;
  int kb = blockIdx.x & 127;
  int qt = blockIdx.x >> 7;
  int kbase = kb * 64;
  int qwave = qt * 1024 + w * 256;
  int l16 = lane & 15, lg = lane >> 4;

  if (tid < 64) lcnt[tid] = 0;
  __syncthreads();

  short8 a0[4], a1[4];
#pragma unroll
  for (int s = 0; s < 4; ++s) {
    const short8* krow = reinterpret_cast<const short8*>(
        kbf + (size_t)(kbase + s * 16 + l16) * DDIM);
    a0[s] = krow[lg]; a1[s] = krow[lg + 4];
  }
  float psA[16], psB[16];
#pragma unroll
  for (int s = 0; s < 4; ++s)
#pragma unroll
    for (int r = 0; r < 4; ++r) {
      float2 ps = PS[kbase + s * 16 + lg * 4 + r];
      psA[s * 4 + r] = ps.x; psB[s * 4 + r] = ps.y;
    }

  for (int qo = 0; qo < 4; ++qo) {
    int qbase = qwave + qo * 64;
#pragma unroll
    for (int qs = 0; qs < 4; ++qs) {
      int q = qbase + qs * 16 + l16;
      const short8* qrow = reinterpret_cast<const short8*>(qbf + (size_t)q * DDIM);
      short8 b0 = qrow[lg], b1 = qrow[lg + 4];
      float q2l = q2a[q], sql = sqa[q];
      float h = 0.5f * q2l;

      f32x4 acc[4];
#pragma unroll
      for (int s = 0; s < 4; ++s) {
        f32x4 z = {0.f, 0.f, 0.f, 0.f};
        z = __builtin_amdgcn_mfma_f32_16x16x32_bf16(a0[s], b0, z, 0, 0, 0);
        z = __builtin_amdgcn_mfma_f32_16x16x32_bf16(a1[s], b1, z, 0, 0, 0);
        acc[s] = z;
      }
      unsigned m = 0;
#pragma unroll
      for (int s = 0; s < 4; ++s)
#pragma unroll
        for (int r = 0; r < 4; ++r) {
          int i = s * 4 + r;
          float thr = fmaf(psB[i], sql, psA[i] + h);
          m |= (acc[s][r] > thr) ? (1u << i) : 0u;
        }
      while (m) {
        int b = __ffs(m) - 1; m &= m - 1;
        int kl = (b >> 2) * 16 + lg * 4 + (b & 3);
        int slot = atomicAdd(&lcnt[kl], 1);
        if (slot < LSLOT) lhit[kl * LSLOT + slot] = (unsigned short)q;
      }
    }
  }
  __syncthreads();
  if (tid < 64) {
    int lc = lcnt[tid];
    int key = kbase + tid;
    unsigned add = (lc > LSLOT) ? (unsigned)(CAP + 1000) : (unsigned)lc;
    lbase[tid] = (lc > 0) ? (int)atomicAdd(&cnt[key], add) : 0;
    lcnt[tid] = lc < LSLOT ? lc : LSLOT;
  }
  __syncthreads();
  for (int idx = tid; idx < 64 * LSLOT; idx += 256) {
    int kl = idx >> 5, sl = idx & (LSLOT - 1);
    if (sl < lcnt[kl]) {
      int pos = lbase[kl] + sl;
      if (pos < CAP)
        cbuf[(size_t)(kbase + kl) * CAP + pos] = lhit[kl * LSLOT + sl];
    }
  }
}

// ---------------------------------------------------------------------------
// Kernel H (recheck v6, r14-proven): block-per-key, 4 lanes per candidate
// with bit-exact segment-handoff chain. Selection rank-count; chunked
// full-scan fallback.
// ---------------------------------------------------------------------------
__global__ __launch_bounds__(256) void knn_recheck(
    const float* __restrict__ keys, const float* __restrict__ queries,
    const float* __restrict__ k2a, const float* __restrict__ q2a,
    const unsigned* __restrict__ cnt, const unsigned short* __restrict__ cbuf,
    int CAP, int Nq, float* __restrict__ outIdx) {
  __shared__ unsigned long long packs[RBUF];       // 8.3 KB
  __shared__ unsigned long long cur16[KSEL];
  __shared__ float4 klds[16];
  int tid = threadIdx.x;
  int key = blockIdx.x;
  float myk2 = k2a[key];

  if (tid < 16)
    klds[tid] = reinterpret_cast<const float4*>(keys + (size_t)key * DDIM)[tid];
  __syncthreads();

  unsigned n = cnt[key];
  unsigned lim = (unsigned)((CAP < RFAST) ? CAP : RFAST);
  if (n <= lim) {
    const unsigned short* mc = cbuf + (size_t)key * CAP;
    int sub = tid & 3;
    int lanebase = (tid & 63) & ~3;
    for (unsigned base = 0; base < n; base += 64) {
      unsigned e = base + (unsigned)(tid >> 2);
      unsigned ec = (e < n) ? e : (n - 1);
      int j = mc[ec];
      const float4* Q = reinterpret_cast<const float4*>(queries + (size_t)j * DDIM);
      float4 rr[4];
      rr[0] = Q[sub];
      rr[1] = Q[sub + 4];
      rr[2] = Q[sub + 8];
      rr[3] = Q[sub + 12];
      float q2j = q2a[j];
      float c = 0.f;
#pragma unroll
      for (int seg = 0; seg < 16; ++seg) {
        float4 kk = klds[seg];
        float4 qq = rr[seg >> 2];
        float t = c;
        t = fmaf(kk.x, qq.x, t);
        t = fmaf(kk.y, qq.y, t);
        t = fmaf(kk.z, qq.z, t);
        t = fmaf(kk.w, qq.w, t);
        c = __shfl(t, lanebase + (seg & 3), 64);
      }
      if (e < n && sub == 0) {
        float d2 = __fsub_rn(__fadd_rn(myk2, q2j), __fmul_rn(2.0f, c));
        packs[e] = packdj(d2, j);
      }
    }
    __syncthreads();
    int N = (int)n;
    for (int i = tid; i < N; i += 256) {
      unsigned long long mp = packs[i];
      int c = 0;
      for (int m = 0; m < N; ++m) c += packs[m] < mp;
      if (c < KSEL)
        outIdx[(size_t)key * KSEL + c] = (float)(int)(mp & 0xFFFFFFFFull);
    }
    return;
  }

  // ---- fallback: exact full scan (correctness net, expected never) ----
  float bd[KSEL]; int bi[KSEL];
#pragma unroll
  for (int p = 0; p < KSEL; ++p) { bd[p] = FLT_MAX; bi[p] = INT_MAX; }
  const float* krow = keys + (size_t)key * DDIM;
  for (int j = tid; j < Nq; j += 256) {
    float d2 = exact_d2(krow, queries + (size_t)j * DDIM, myk2, q2a[j]);
    if (d2 < bd[KSEL - 1] || (d2 == bd[KSEL - 1] && j < bi[KSEL - 1]))
      insert16(bd, bi, d2, j);
  }
  if (tid < KSEL) cur16[tid] = ~0ull;
  __syncthreads();
  for (int r = 0; r < 4; ++r) {
    if ((tid >> 6) == r) {
#pragma unroll
      for (int p = 0; p < KSEL; ++p)
        packs[KSEL + (tid & 63) * KSEL + p] = packdj(bd[p], bi[p]);
    }
    if (tid < KSEL) packs[tid] = cur16[tid];
    __syncthreads();
    const int N = KSEL + 64 * KSEL;   // 1040
    for (int i = tid; i < N; i += 256) {
      unsigned long long mp = packs[i];
      int c = 0;
      for (int m = 0; m < N; ++m) c += packs[m] < mp;
      if (c < KSEL) cur16[c] = mp;
    }
    __syncthreads();
  }
  if (tid < KSEL)
    outIdx[(size_t)key * KSEL + tid] =
        (float)(int)(cur16[tid] & 0xFFFFFFFFull);
}

// ---------------------------------------------------------------------------
// Kernel I: recompute distances sum((k-q)^2) in f64, emit f32 (validated).
// ---------------------------------------------------------------------------
__global__ __launch_bounds__(256) void knn_dist_d(
    const float* __restrict__ keys, const float* __restrict__ queries,
    const float* __restrict__ outIdx, int Nk, float* __restrict__ outDist) {
  int e = blockIdx.x * 256 + threadIdx.x;
  if (e >= Nk * KSEL) return;
  int key = e >> 4;
  int id = (int)outIdx[e];
  const float* kp = keys + (size_t)key * DDIM;
  const float* qp = queries + (size_t)id * DDIM;
  double s = 0.0;
#pragma unroll
  for (int t = 0; t < DDIM; ++t) {
    double d = (double)kp[t] - (double)qp[t];
    s = fma(d, d, s);
  }
  outDist[e] = (float)s;
}

// ---------------------------------------------------------------------------
extern "C" void kernel_launch(void* const* d_in, const int* in_sizes, int n_in,
                              void* d_out, int out_size, void* d_ws, size_t ws_size,
                              hipStream_t stream) {
  const float* keys    = (const float*)d_in[0];
  const float* queries = (const float*)d_in[1];
  int Nk = in_sizes[0] / DDIM;   // 8192
  int Nq = in_sizes[1] / DDIM;   // 32768
  float* out = (float*)d_out;

  char* wp = (char*)d_ws;
  unsigned long long* spack = (unsigned long long*)wp;
  wp += (size_t)Nk * WSL * SCAP * 8;                       // 16.78 MB
  float*    k2  = (float*)wp;  wp += (size_t)Nk * 4;
  float*    q2  = (float*)wp;  wp += (size_t)Nq * 4;
  float*    sk  = (float*)wp;  wp += (size_t)Nk * 4;
  float*    sq  = (float*)wp;  wp += (size_t)Nq * 4;
  float*    PR  = (float*)wp;  wp += (size_t)Nk * 4;
  float2*   PS  = (float2*)wp; wp += (size_t)Nk * 8;
  unsigned* cnt = (unsigned*)wp; wp += (size_t)Nk * 4;
  unsigned* cmin = (unsigned*)wp; wp += (size_t)Nk * NCHUNK * 4;
  unsigned short* kbf = (unsigned short*)wp; wp += (size_t)Nk * DDIM * 2;
  unsigned short* qbf = (unsigned short*)wp; wp += (size_t)Nq * DDIM * 2;
  size_t fixedBytes = (size_t)(wp - (char*)d_ws);
  unsigned short* cbuf = (unsigned short*)wp;
  long long rem = (long long)ws_size - (long long)fixedBytes;
  int CAP = (int)(rem / (2 * (long long)Nk));
  if (CAP > 2048) CAP = 2048;
  if (CAP < 16) CAP = 16;

  int nInit = Nk * NCHUNK;
  knn_init<<<(nInit + 255) / 256, 256, 0, stream>>>(cmin, nInit, cnt, Nk);
  knn_norms_np<<<(Nk + Nq + 255) / 256, 256, 0, stream>>>(
      keys, queries, Nk, Nq, k2, q2, sk, sq, kbf, qbf);
  knn_chunkmin<<<128 * (WINDOW / 256), 256, 0, stream>>>(
      kbf, qbf, k2, sk, q2, sq, cmin);
  knn_trough<<<(Nk + 255) / 256, 256, 0, stream>>>(cmin, PR, Nk);
  knn_seed2<<<32 * WSL, 256, 0, stream>>>(keys, queries, k2, q2, PR, spack);
  knn_thresh2<<<Nk / 4, 256, 0, stream>>>(spack, PR, k2, sk, PS);
  knn_filter<<<128 * (Nq / 1024), 256, 0, stream>>>(
      kbf, qbf, q2, sq, PS, cnt, cbuf, CAP);
  knn_recheck<<<Nk, 256, 0, stream>>>(
      keys, queries, k2, q2, cnt, cbuf, CAP, Nq, out);
  knn_dist_d<<<(Nk * KSEL + 255) / 256, 256, 0, stream>>>(
      keys, queries, out, Nk, out + (size_t)Nk * KSEL);
}

// Round 17
// 308.525 us; speedup vs baseline: 4.2436x; 1.2249x over previous
//
#include <hip/hip_runtime.h>
#include <hip/hip_bf16.h>
#include <cfloat>
#include <climits>

#define DDIM 64
#define KSEL 16
#define WINDOW 4096          // T-estimation window
#define NCHUNK 32            // chunks of 128 in window
#define C1 0.017f            // > 2^-6: covers 2*bf16 dot error via Cauchy-Schwarz
#define C2 0.05f             // covers f32 accumulation + threshold rounding
#define RFAST 1024           // fast-path candidate limit (block recheck)
#define RBUF 1040            // LDS pack slots: fast path <=1024; fallback 16+1024
#define LSLOT 32             // per-(key,block) LDS hit slots (main filter)
#define MSLOT 96             // per-(key,block) LDS slots (minifilter; drops SAFE)
#define CAP2 256             // spack slots per key (minifilter output)

typedef __attribute__((ext_vector_type(8))) short short8;
typedef __attribute__((ext_vector_type(4))) float f32x4;

// ---------------------------------------------------------------------------
// numpy pairwise-sum emulation for n=64 contiguous f32 (validated r3-r16).
// ---------------------------------------------------------------------------
__device__ __forceinline__ float np_sum64(const float* p) {
  float lane[16];
#pragma unroll
  for (int j = 0; j < 16; ++j)
    lane[j] = __fadd_rn(__fadd_rn(p[j], p[16 + j]),
                        __fadd_rn(p[32 + j], p[48 + j]));
  float u[8];
#pragma unroll
  for (int j = 0; j < 8; ++j) u[j] = __fadd_rn(lane[j], lane[j + 8]);
  float w[4];
#pragma unroll
  for (int j = 0; j < 4; ++j) w[j] = __fadd_rn(u[j], u[j + 4]);
  return __fadd_rn(__fadd_rn(w[0], w[2]), __fadd_rn(w[1], w[3]));
}

__device__ __forceinline__ void insert16(float* bd, int* bi, float cd, int ci) {
#pragma unroll
  for (int p = 0; p < KSEL; ++p) {
    bool sm = (cd < bd[p]) || (cd == bd[p] && ci < bi[p]);
    float td = bd[p]; int ti = bi[p];
    bd[p] = sm ? cd : td; bi[p] = sm ? ci : ti;
    cd = sm ? td : cd;   ci = sm ? ti : ci;
  }
}

// Monotone map: lexicographic (d,j) ascending == u64 ascending (j distinct).
__device__ __forceinline__ unsigned long long packdj(float d, int j) {
  unsigned db = __float_as_uint(d);
  db = (db & 0x80000000u) ? ~db : (db | 0x80000000u);
  return ((unsigned long long)db << 32) | (unsigned)j;
}

__device__ __forceinline__ unsigned mapmono(float d) {
  unsigned db = __float_as_uint(d);
  return (db & 0x80000000u) ? ~db : (db | 0x80000000u);
}

__device__ __forceinline__ float unmapmono(unsigned m) {
  return (m & 0x80000000u) ? __uint_as_float(m & 0x7fffffffu)
                           : __uint_as_float(~m);
}

// np-exact d2: sequential fmaf chain (BLAS per-element order), validated r3.
__device__ __forceinline__ float exact_d2(const float* __restrict__ k,
                                          const float* __restrict__ q,
                                          float k2, float q2) {
  float c = 0.f;
#pragma unroll
  for (int t = 0; t < DDIM; ++t) c = fmaf(k[t], q[t], c);
  return __fsub_rn(__fadd_rn(k2, q2), __fmul_rn(2.0f, c));
}

__device__ __forceinline__ unsigned bf2pack(float a, float b) {
  __hip_bfloat16 ha = __float2bfloat16(a), hb = __float2bfloat16(b);
  unsigned short ua = *reinterpret_cast<unsigned short*>(&ha);
  unsigned short ub = *reinterpret_cast<unsigned short*>(&hb);
  return (unsigned)ua | ((unsigned)ub << 16);
}

// ---------------------------------------------------------------------------
// Kernel A: np-exact row norms + bf16 conversion + sqrt norms. Validated.
// ---------------------------------------------------------------------------
__global__ __launch_bounds__(256) void knn_norms_np(
    const float* __restrict__ keys, const float* __restrict__ queries,
    int Nk, int Nq, float* __restrict__ k2, float* __restrict__ q2,
    float* __restrict__ sk, float* __restrict__ sq,
    unsigned short* __restrict__ kbf, unsigned short* __restrict__ qbf) {
  int i = blockIdx.x * 256 + threadIdx.x;
  if (i >= Nk + Nq) return;
  bool isK = i < Nk;
  int r = isK ? i : i - Nk;
  const float4* row4 = reinterpret_cast<const float4*>(
      (isK ? keys : queries) + (size_t)r * DDIM);
  float p[DDIM]; unsigned hw[DDIM / 2];
#pragma unroll
  for (int t = 0; t < 16; ++t) {
    float4 v = row4[t];
    p[4 * t + 0] = __fmul_rn(v.x, v.x);
    p[4 * t + 1] = __fmul_rn(v.y, v.y);
    p[4 * t + 2] = __fmul_rn(v.z, v.z);
    p[4 * t + 3] = __fmul_rn(v.w, v.w);
    hw[2 * t + 0] = bf2pack(v.x, v.y);
    hw[2 * t + 1] = bf2pack(v.z, v.w);
  }
  float s = np_sum64(p);
  uint4* dst = reinterpret_cast<uint4*>((isK ? kbf : qbf) + (size_t)r * DDIM);
#pragma unroll
  for (int t = 0; t < 8; ++t)
    dst[t] = make_uint4(hw[4 * t], hw[4 * t + 1], hw[4 * t + 2], hw[4 * t + 3]);
  if (isK) { k2[r] = s; sk[r] = sqrtf(s); }
  else     { q2[r] = s; sq[r] = sqrtf(s); }
}

// ---------------------------------------------------------------------------
// Kernel B: init cmin = ~0, cnt = cnt2 = 0, spack = ~0 (sentinels; ws is NOT
// re-poisoned between replays so stale packs must be cleared every call).
// ---------------------------------------------------------------------------
__global__ __launch_bounds__(256) void knn_init(
    unsigned* __restrict__ cmin, int nmin,
    unsigned* __restrict__ cnt, unsigned* __restrict__ cnt2, int ncnt,
    unsigned* __restrict__ spw, int nspw) {
  int i = blockIdx.x * 256 + threadIdx.x;
  if (i < nmin) cmin[i] = 0xFFFFFFFFu;
  if (i < ncnt) { cnt[i] = 0u; cnt2[i] = 0u; }
  if (i < nspw) spw[i] = 0xFFFFFFFFu;
}

// ---------------------------------------------------------------------------
// Kernel C (chunkmin): MFMA upper-bound chunk minima over window. Validated r8.
// u = fmaf(C1*sk, sq, (k2+C2) + q2) - 2*acc  -- EXPRESSION SHARED with the
// minifilter (bitwise) so chunk-min pairs provably re-pass there.
// ---------------------------------------------------------------------------
__global__ __launch_bounds__(256) void knn_chunkmin(
    const unsigned short* __restrict__ kbf, const unsigned short* __restrict__ qbf,
    const float* __restrict__ k2a, const float* __restrict__ ska,
    const float* __restrict__ q2a, const float* __restrict__ sqa,
    unsigned* __restrict__ cmin) {
  int tid = threadIdx.x, lane = tid & 63, w = tid >> 6;
  int kb = blockIdx.x & 127;
  int qt = blockIdx.x >> 7;              // 0..15
  int kbase = kb * 64;
  int qbase = qt * 256 + w * 64;
  int chunk = qbase >> 7;                // 0..31
  int l16 = lane & 15, lg = lane >> 4;

  short8 a0[4], a1[4];
#pragma unroll
  for (int s = 0; s < 4; ++s) {
    const short8* krow = reinterpret_cast<const short8*>(
        kbf + (size_t)(kbase + s * 16 + l16) * DDIM);
    a0[s] = krow[lg]; a1[s] = krow[lg + 4];
  }
  float KA[16], KB[16];
#pragma unroll
  for (int s = 0; s < 4; ++s)
#pragma unroll
    for (int r = 0; r < 4; ++r) {
      int kk = kbase + s * 16 + lg * 4 + r;
      KA[s * 4 + r] = k2a[kk] + C2;
      KB[s * 4 + r] = C1 * ska[kk];
    }
  float mreg[16];
#pragma unroll
  for (int i = 0; i < 16; ++i) mreg[i] = FLT_MAX;

#pragma unroll
  for (int qs = 0; qs < 4; ++qs) {
    int q = qbase + qs * 16 + l16;
    const short8* qrow = reinterpret_cast<const short8*>(qbf + (size_t)q * DDIM);
    short8 b0 = qrow[lg], b1 = qrow[lg + 4];
    float q2l = q2a[q], sql = sqa[q];
    f32x4 acc[4];
#pragma unroll
    for (int s = 0; s < 4; ++s) {
      f32x4 z = {0.f, 0.f, 0.f, 0.f};
      z = __builtin_amdgcn_mfma_f32_16x16x32_bf16(a0[s], b0, z, 0, 0, 0);
      z = __builtin_amdgcn_mfma_f32_16x16x32_bf16(a1[s], b1, z, 0, 0, 0);
      acc[s] = z;
    }
#pragma unroll
    for (int s = 0; s < 4; ++s)
#pragma unroll
      for (int r = 0; r < 4; ++r) {
        int i = s * 4 + r;
        float u = fmaf(KB[i], sql, KA[i] + q2l) - 2.0f * acc[s][r];
        mreg[i] = fminf(mreg[i], u);
      }
  }
#pragma unroll
  for (int m = 1; m < 16; m <<= 1)
#pragma unroll
    for (int i = 0; i < 16; ++i)
      mreg[i] = fminf(mreg[i], __shfl_xor(mreg[i], m));
  if (l16 == 0) {
#pragma unroll
    for (int i = 0; i < 16; ++i) {
      int kk = kbase + (i >> 2) * 16 + lg * 4 + (i & 3);
      atomicMin(&cmin[(size_t)kk * NCHUNK + chunk], mapmono(mreg[i]));
    }
  }
}

// ---------------------------------------------------------------------------
// Kernel D (trough): T_rough[key] = max over 32 chunk minima (>=32 window
// pairs have u <= T_rough). Validated r8.
// ---------------------------------------------------------------------------
__global__ __launch_bounds__(256) void knn_trough(
    const unsigned* __restrict__ cmin, float* __restrict__ PR, int Nk) {
  int k = blockIdx.x * 256 + threadIdx.x;
  if (k >= Nk) return;
  unsigned m = 0;
#pragma unroll
  for (int c = 0; c < NCHUNK; ++c) {
    unsigned v = cmin[(size_t)k * NCHUNK + c];
    m = v > m ? v : m;
  }
  PR[k] = unmapmono(m);
}

// ---------------------------------------------------------------------------
// Kernel E (minifilter): MFMA over keys x window; append (u, q) packs where
// u <= T_rough (same u expression as chunkmin, bitwise). ALL drop paths
// (MSLOT, CAP2) only LOOSEN the resulting T -- provably safe, no cliff.
// ---------------------------------------------------------------------------
__global__ __launch_bounds__(256) void knn_minifilt(
    const unsigned short* __restrict__ kbf, const unsigned short* __restrict__ qbf,
    const float* __restrict__ k2a, const float* __restrict__ ska,
    const float* __restrict__ q2a, const float* __restrict__ sqa,
    const float* __restrict__ PR,
    unsigned* __restrict__ cnt2, unsigned long long* __restrict__ spack) {
  __shared__ int lcnt[64];
  __shared__ int lbase[64];
  __shared__ unsigned long long lhit[64 * MSLOT];   // 48 KB
  int tid = threadIdx.x;
  int lane = tid & 63, w = tid >> 6;
  int kb = blockIdx.x & 127;
  int qt = blockIdx.x >> 7;              // 0..3
  int kbase = kb * 64;
  int qwave = qt * 1024 + w * 256;
  int l16 = lane & 15, lg = lane >> 4;

  if (tid < 64) lcnt[tid] = 0;
  __syncthreads();

  short8 a0[4], a1[4];
#pragma unroll
  for (int s = 0; s < 4; ++s) {
    const short8* krow = reinterpret_cast<const short8*>(
        kbf + (size_t)(kbase + s * 16 + l16) * DDIM);
    a0[s] = krow[lg]; a1[s] = krow[lg + 4];
  }
  float KA[16], KB[16], PRl[16];
#pragma unroll
  for (int s = 0; s < 4; ++s)
#pragma unroll
    for (int r = 0; r < 4; ++r) {
      int kk = kbase + s * 16 + lg * 4 + r;
      KA[s * 4 + r] = k2a[kk] + C2;
      KB[s * 4 + r] = C1 * ska[kk];
      PRl[s * 4 + r] = PR[kk];
    }

  for (int qo = 0; qo < 4; ++qo) {
    int qbase = qwave + qo * 64;
#pragma unroll
    for (int qs = 0; qs < 4; ++qs) {
      int q = qbase + qs * 16 + l16;
      const short8* qrow = reinterpret_cast<const short8*>(qbf + (size_t)q * DDIM);
      short8 b0 = qrow[lg], b1 = qrow[lg + 4];
      float q2l = q2a[q], sql = sqa[q];

      f32x4 acc[4];
#pragma unroll
      for (int s = 0; s < 4; ++s) {
        f32x4 z = {0.f, 0.f, 0.f, 0.f};
        z = __builtin_amdgcn_mfma_f32_16x16x32_bf16(a0[s], b0, z, 0, 0, 0);
        z = __builtin_amdgcn_mfma_f32_16x16x32_bf16(a1[s], b1, z, 0, 0, 0);
        acc[s] = z;
      }
#pragma unroll
      for (int s = 0; s < 4; ++s)
#pragma unroll
        for (int r = 0; r < 4; ++r) {
          int i = s * 4 + r;
          float u = fmaf(KB[i], sql, KA[i] + q2l) - 2.0f * acc[s][r];
          if (u <= PRl[i]) {
            int kl = i == (s * 4 + r) ? (s * 16 + lg * 4 + r) : 0;  // block-local key
            int slot = atomicAdd(&lcnt[kl], 1);
            if (slot < MSLOT) lhit[kl * MSLOT + slot] = packdj(u, q);
          }
        }
    }
  }
  __syncthreads();
  if (tid < 64) {
    int lc = lcnt[tid];
    int kept = lc < MSLOT ? lc : MSLOT;
    lbase[tid] = (kept > 0) ? (int)atomicAdd(&cnt2[kbase + tid], (unsigned)kept) : 0;
    lcnt[tid] = kept;
  }
  __syncthreads();
  for (int idx = tid; idx < 64 * MSLOT; idx += 256) {
    int kl = idx / MSLOT, sl = idx - kl * MSLOT;
    if (sl < lcnt[kl]) {
      int pos = lbase[kl] + sl;
      if (pos < CAP2)
        spack[(size_t)(kbase + kl) * CAP2 + pos] = lhit[kl * MSLOT + sl];
    }
  }
}

// ---------------------------------------------------------------------------
// Kernel F (thresh2): wave-per-key rank-count over CAP2 = 256 packed slots
// (sentinel ~0 padding from init) -> T = 16th-smallest u (valid upper bound
// on global exact 16th); <16 real entries -> T_rough. PS pre-halved (r13).
// ---------------------------------------------------------------------------
__global__ __launch_bounds__(256) void knn_thresh2(
    const unsigned long long* __restrict__ spack, const float* __restrict__ PR,
    const float* __restrict__ k2a, const float* __restrict__ ska,
    float2* __restrict__ PS) {
  __shared__ unsigned long long packs[4][CAP2];
  __shared__ float Tsh[4];
  int tid = threadIdx.x, w = tid >> 6, lane = tid & 63;
  int key = blockIdx.x * 4 + w;

  unsigned long long mine[4];
#pragma unroll
  for (int r = 0; r < 4; ++r) {
    int e = lane + 64 * r;
    mine[r] = spack[(size_t)key * CAP2 + e];
    packs[w][e] = mine[r];
  }
  if (lane == 0) Tsh[w] = PR[key];
  __syncthreads();
  int c0 = 0, c1 = 0, c2 = 0, c3 = 0;
  for (int m = 0; m < CAP2; ++m) {
    unsigned long long pm = packs[w][m];
    c0 += pm < mine[0]; c1 += pm < mine[1];
    c2 += pm < mine[2]; c3 += pm < mine[3];
  }
  int c[4] = {c0, c1, c2, c3};
  __syncthreads();
#pragma unroll
  for (int r = 0; r < 4; ++r)
    if (c[r] == KSEL - 1 && mine[r] != ~0ull)
      Tsh[w] = unmapmono((unsigned)(mine[r] >> 32));
  __syncthreads();
  if (lane == 0) {
    float T = Tsh[w];
    PS[key] = make_float2(0.5f * (k2a[key] - T - C2), -0.5f * C1 * ska[key]);
  }
}

// ---------------------------------------------------------------------------
// Kernel G (MFMA filter v3, r13/r14/r16-proven): block = 4 waves x same 64
// keys x 1024 queries, LDS hit aggregation (LSLOT=32) + single global atomic
// per (key,block); pre-halved threshold epilogue.
// ---------------------------------------------------------------------------
__global__ __launch_bounds__(256) void knn_filter(
    const unsigned short* __restrict__ kbf, const unsigned short* __restrict__ qbf,
    const float* __restrict__ q2a, const float* __restrict__ sqa,
    const float2* __restrict__ PS,
    unsigned* __restrict__ cnt, unsigned short* __restrict__ cbuf, int CAP) {
  __shared__ int lcnt[64];
  __shared__ int lbase[64];
  __shared__ unsigned short lhit[64 * LSLOT];
  int tid = threadIdx.x;
  int lane = tid & 63, w = tid >> 6;
  int kb = blockIdx.x & 127;
  int qt = blockIdx.x >> 7;
  int kbase = kb * 64;
  int qwave = qt * 1024 + w * 256;
  int l16 = lane & 15, lg = lane >> 4;

  if (tid < 64) lcnt[tid] = 0;
  __syncthreads();

  short8 a0[4], a1[4];
#pragma unroll
  for (int s = 0; s < 4; ++s) {
    const short8* krow = reinterpret_cast<const short8*>(
        kbf + (size_t)(kbase + s * 16 + l16) * DDIM);
    a0[s] = krow[lg]; a1[s] = krow[lg + 4];
  }
  float psA[16], psB[16];
#pragma unroll
  for (int s = 0; s < 4; ++s)
#pragma unroll
    for (int r = 0; r < 4; ++r) {
      float2 ps = PS[kbase + s * 16 + lg * 4 + r];
      psA[s * 4 + r] = ps.x; psB[s * 4 + r] = ps.y;
    }

  for (int qo = 0; qo < 4; ++qo) {
    int qbase = qwave + qo * 64;
#pragma unroll
    for (int qs = 0; qs < 4; ++qs) {
      int q = qbase + qs * 16 + l16;
      const short8* qrow = reinterpret_cast<const short8*>(qbf + (size_t)q * DDIM);
      short8 b0 = qrow[lg], b1 = qrow[lg + 4];
      float q2l = q2a[q], sql = sqa[q];
      float h = 0.5f * q2l;

      f32x4 acc[4];
#pragma unroll
      for (int s = 0; s < 4; ++s) {
        f32x4 z = {0.f, 0.f, 0.f, 0.f};
        z = __builtin_amdgcn_mfma_f32_16x16x32_bf16(a0[s], b0, z, 0, 0, 0);
        z = __builtin_amdgcn_mfma_f32_16x16x32_bf16(a1[s], b1, z, 0, 0, 0);
        acc[s] = z;
      }
      unsigned m = 0;
#pragma unroll
      for (int s = 0; s < 4; ++s)
#pragma unroll
        for (int r = 0; r < 4; ++r) {
          int i = s * 4 + r;
          float thr = fmaf(psB[i], sql, psA[i] + h);
          m |= (acc[s][r] > thr) ? (1u << i) : 0u;
        }
      while (m) {
        int b = __ffs(m) - 1; m &= m - 1;
        int kl = (b >> 2) * 16 + lg * 4 + (b & 3);
        int slot = atomicAdd(&lcnt[kl], 1);
        if (slot < LSLOT) lhit[kl * LSLOT + slot] = (unsigned short)q;
      }
    }
  }
  __syncthreads();
  if (tid < 64) {
    int lc = lcnt[tid];
    int key = kbase + tid;
    unsigned add = (lc > LSLOT) ? (unsigned)(CAP + 1000) : (unsigned)lc;
    lbase[tid] = (lc > 0) ? (int)atomicAdd(&cnt[key], add) : 0;
    lcnt[tid] = lc < LSLOT ? lc : LSLOT;
  }
  __syncthreads();
  for (int idx = tid; idx < 64 * LSLOT; idx += 256) {
    int kl = idx >> 5, sl = idx & (LSLOT - 1);
    if (sl < lcnt[kl]) {
      int pos = lbase[kl] + sl;
      if (pos < CAP)
        cbuf[(size_t)(kbase + kl) * CAP + pos] = lhit[kl * LSLOT + sl];
    }
  }
}

// ---------------------------------------------------------------------------
// Kernel H (recheck v6, r14/r16-proven): block-per-key, 4 lanes per candidate
// with bit-exact segment-handoff chain. Rank-count selection; chunked
// full-scan fallback.
// ---------------------------------------------------------------------------
__global__ __launch_bounds__(256) void knn_recheck(
    const float* __restrict__ keys, const float* __restrict__ queries,
    const float* __restrict__ k2a, const float* __restrict__ q2a,
    const unsigned* __restrict__ cnt, const unsigned short* __restrict__ cbuf,
    int CAP, int Nq, float* __restrict__ outIdx) {
  __shared__ unsigned long long packs[RBUF];       // 8.3 KB
  __shared__ unsigned long long cur16[KSEL];
  __shared__ float4 klds[16];
  int tid = threadIdx.x;
  int key = blockIdx.x;
  float myk2 = k2a[key];

  if (tid < 16)
    klds[tid] = reinterpret_cast<const float4*>(keys + (size_t)key * DDIM)[tid];
  __syncthreads();

  unsigned n = cnt[key];
  unsigned lim = (unsigned)((CAP < RFAST) ? CAP : RFAST);
  if (n <= lim) {
    const unsigned short* mc = cbuf + (size_t)key * CAP;
    int sub = tid & 3;
    int lanebase = (tid & 63) & ~3;
    for (unsigned base = 0; base < n; base += 64) {
      unsigned e = base + (unsigned)(tid >> 2);
      unsigned ec = (e < n) ? e : (n - 1);
      int j = mc[ec];
      const float4* Q = reinterpret_cast<const float4*>(queries + (size_t)j * DDIM);
      float4 rr[4];
      rr[0] = Q[sub];
      rr[1] = Q[sub + 4];
      rr[2] = Q[sub + 8];
      rr[3] = Q[sub + 12];
      float q2j = q2a[j];
      float c = 0.f;
#pragma unroll
      for (int seg = 0; seg < 16; ++seg) {
        float4 kk = klds[seg];
        float4 qq = rr[seg >> 2];
        float t = c;
        t = fmaf(kk.x, qq.x, t);
        t = fmaf(kk.y, qq.y, t);
        t = fmaf(kk.z, qq.z, t);
        t = fmaf(kk.w, qq.w, t);
        c = __shfl(t, lanebase + (seg & 3), 64);
      }
      if (e < n && sub == 0) {
        float d2 = __fsub_rn(__fadd_rn(myk2, q2j), __fmul_rn(2.0f, c));
        packs[e] = packdj(d2, j);
      }
    }
    __syncthreads();
    int N = (int)n;
    for (int i = tid; i < N; i += 256) {
      unsigned long long mp = packs[i];
      int c = 0;
      for (int m = 0; m < N; ++m) c += packs[m] < mp;
      if (c < KSEL)
        outIdx[(size_t)key * KSEL + c] = (float)(int)(mp & 0xFFFFFFFFull);
    }
    return;
  }

  // ---- fallback: exact full scan (correctness net, expected never) ----
  float bd[KSEL]; int bi[KSEL];
#pragma unroll
  for (int p = 0; p < KSEL; ++p) { bd[p] = FLT_MAX; bi[p] = INT_MAX; }
  const float* krow = keys + (size_t)key * DDIM;
  for (int j = tid; j < Nq; j += 256) {
    float d2 = exact_d2(krow, queries + (size_t)j * DDIM, myk2, q2a[j]);
    if (d2 < bd[KSEL - 1] || (d2 == bd[KSEL - 1] && j < bi[KSEL - 1]))
      insert16(bd, bi, d2, j);
  }
  if (tid < KSEL) cur16[tid] = ~0ull;
  __syncthreads();
  for (int r = 0; r < 4; ++r) {
    if ((tid >> 6) == r) {
#pragma unroll
      for (int p = 0; p < KSEL; ++p)
        packs[KSEL + (tid & 63) * KSEL + p] = packdj(bd[p], bi[p]);
    }
    if (tid < KSEL) packs[tid] = cur16[tid];
    __syncthreads();
    const int N = KSEL + 64 * KSEL;   // 1040
    for (int i = tid; i < N; i += 256) {
      unsigned long long mp = packs[i];
      int c = 0;
      for (int m = 0; m < N; ++m) c += packs[m] < mp;
      if (c < KSEL) cur16[c] = mp;
    }
    __syncthreads();
  }
  if (tid < KSEL)
    outIdx[(size_t)key * KSEL + tid] =
        (float)(int)(cur16[tid] & 0xFFFFFFFFull);
}

// ---------------------------------------------------------------------------
// Kernel I: recompute distances sum((k-q)^2) in f64, emit f32 (validated).
// ---------------------------------------------------------------------------
__global__ __launch_bounds__(256) void knn_dist_d(
    const float* __restrict__ keys, const float* __restrict__ queries,
    const float* __restrict__ outIdx, int Nk, float* __restrict__ outDist) {
  int e = blockIdx.x * 256 + threadIdx.x;
  if (e >= Nk * KSEL) return;
  int key = e >> 4;
  int id = (int)outIdx[e];
  const float* kp = keys + (size_t)key * DDIM;
  const float* qp = queries + (size_t)id * DDIM;
  double s = 0.0;
#pragma unroll
  for (int t = 0; t < DDIM; ++t) {
    double d = (double)kp[t] - (double)qp[t];
    s = fma(d, d, s);
  }
  outDist[e] = (float)s;
}

// ---------------------------------------------------------------------------
extern "C" void kernel_launch(void* const* d_in, const int* in_sizes, int n_in,
                              void* d_out, int out_size, void* d_ws, size_t ws_size,
                              hipStream_t stream) {
  const float* keys    = (const float*)d_in[0];
  const float* queries = (const float*)d_in[1];
  int Nk = in_sizes[0] / DDIM;   // 8192
  int Nq = in_sizes[1] / DDIM;   // 32768
  float* out = (float*)d_out;

  char* wp = (char*)d_ws;
  unsigned long long* spack = (unsigned long long*)wp;
  wp += (size_t)Nk * CAP2 * 8;                             // 16.78 MB
  float*    k2  = (float*)wp;  wp += (size_t)Nk * 4;
  float*    q2  = (float*)wp;  wp += (size_t)Nq * 4;
  float*    sk  = (float*)wp;  wp += (size_t)Nk * 4;
  float*    sq  = (float*)wp;  wp += (size_t)Nq * 4;
  float*    PR  = (float*)wp;  wp += (size_t)Nk * 4;
  float2*   PS  = (float2*)wp; wp += (size_t)Nk * 8;
  unsigned* cnt = (unsigned*)wp; wp += (size_t)Nk * 4;
  unsigned* cnt2 = (unsigned*)wp; wp += (size_t)Nk * 4;
  unsigned* cmin = (unsigned*)wp; wp += (size_t)Nk * NCHUNK * 4;
  unsigned short* kbf = (unsigned short*)wp; wp += (size_t)Nk * DDIM * 2;
  unsigned short* qbf = (unsigned short*)wp; wp += (size_t)Nq * DDIM * 2;
  size_t fixedBytes = (size_t)(wp - (char*)d_ws);
  unsigned short* cbuf = (unsigned short*)wp;
  long long rem = (long long)ws_size - (long long)fixedBytes;
  int CAP = (int)(rem / (2 * (long long)Nk));
  if (CAP > 2048) CAP = 2048;
  if (CAP < 16) CAP = 16;

  int nmin = Nk * NCHUNK;                 // 262144
  int nspw = Nk * CAP2 * 2;               // 4,194,304 u32 words
  int nInit = nspw;                       // covers all
  knn_init<<<(nInit + 255) / 256, 256, 0, stream>>>(
      cmin, nmin, cnt, cnt2, Nk, (unsigned*)spack, nspw);
  knn_norms_np<<<(Nk + Nq + 255) / 256, 256, 0, stream>>>(
      keys, queries, Nk, Nq, k2, q2, sk, sq, kbf, qbf);
  knn_chunkmin<<<128 * (WINDOW / 256), 256, 0, stream>>>(
      kbf, qbf, k2, sk, q2, sq, cmin);
  knn_trough<<<(Nk + 255) / 256, 256, 0, stream>>>(cmin, PR, Nk);
  knn_minifilt<<<128 * (WINDOW / 1024), 256, 0, stream>>>(
      kbf, qbf, k2, sk, q2, sq, PR, cnt2, spack);
  knn_thresh2<<<Nk / 4, 256, 0, stream>>>(spack, PR, k2, sk, PS);
  knn_filter<<<128 * (Nq / 1024), 256, 0, stream>>>(
      kbf, qbf, q2, sq, PS, cnt, cbuf, CAP);
  knn_recheck<<<Nk, 256, 0, stream>>>(
      keys, queries, k2, q2, cnt, cbuf, CAP, Nq, out);
  knn_dist_d<<<(Nk * KSEL + 255) / 256, 256, 0, stream>>>(
      keys, queries, out, Nk, out + (size_t)Nk * KSEL);
}

// Round 18
// 298.511 us; speedup vs baseline: 4.3860x; 1.0335x over previous
//
#include <hip/hip_runtime.h>
#include <hip/hip_bf16.h>
#include <cfloat>
#include <climits>

#define DDIM 64
#define KSEL 16
#define WINDOW 4096          // T-estimation window
#define NCHUNK 32            // chunks of 128 in window
#define C1 0.017f            // > 2^-6: covers 2*bf16 dot error via Cauchy-Schwarz
#define C2 0.05f             // covers f32 accumulation + threshold rounding
#define RFAST 1024           // fast-path candidate limit (block recheck)
#define RBUF 1040            // LDS pack slots: fast path <=1024; fallback 16+1024
#define LSLOT 32             // per-(key,block) LDS hit slots (main filter)
#define MSLOT 96             // per-(key,block) LDS slots (minifilter; drops SAFE)
#define CAP2 256             // spack slots per key (minifilter output)

typedef __attribute__((ext_vector_type(8))) short short8;
typedef __attribute__((ext_vector_type(4))) float f32x4;

// ---------------------------------------------------------------------------
// numpy pairwise-sum emulation for n=64 contiguous f32 (validated r3-r17).
// ---------------------------------------------------------------------------
__device__ __forceinline__ float np_sum64(const float* p) {
  float lane[16];
#pragma unroll
  for (int j = 0; j < 16; ++j)
    lane[j] = __fadd_rn(__fadd_rn(p[j], p[16 + j]),
                        __fadd_rn(p[32 + j], p[48 + j]));
  float u[8];
#pragma unroll
  for (int j = 0; j < 8; ++j) u[j] = __fadd_rn(lane[j], lane[j + 8]);
  float w[4];
#pragma unroll
  for (int j = 0; j < 4; ++j) w[j] = __fadd_rn(u[j], u[j + 4]);
  return __fadd_rn(__fadd_rn(w[0], w[2]), __fadd_rn(w[1], w[3]));
}

__device__ __forceinline__ void insert16(float* bd, int* bi, float cd, int ci) {
#pragma unroll
  for (int p = 0; p < KSEL; ++p) {
    bool sm = (cd < bd[p]) || (cd == bd[p] && ci < bi[p]);
    float td = bd[p]; int ti = bi[p];
    bd[p] = sm ? cd : td; bi[p] = sm ? ci : ti;
    cd = sm ? td : cd;   ci = sm ? ti : ci;
  }
}

// Monotone map: lexicographic (d,j) ascending == u64 ascending (j distinct).
__device__ __forceinline__ unsigned long long packdj(float d, int j) {
  unsigned db = __float_as_uint(d);
  db = (db & 0x80000000u) ? ~db : (db | 0x80000000u);
  return ((unsigned long long)db << 32) | (unsigned)j;
}

__device__ __forceinline__ unsigned mapmono(float d) {
  unsigned db = __float_as_uint(d);
  return (db & 0x80000000u) ? ~db : (db | 0x80000000u);
}

__device__ __forceinline__ float unmapmono(unsigned m) {
  return (m & 0x80000000u) ? __uint_as_float(m & 0x7fffffffu)
                           : __uint_as_float(~m);
}

// np-exact d2: sequential fmaf chain (BLAS per-element order), validated r3.
__device__ __forceinline__ float exact_d2(const float* __restrict__ k,
                                          const float* __restrict__ q,
                                          float k2, float q2) {
  float c = 0.f;
#pragma unroll
  for (int t = 0; t < DDIM; ++t) c = fmaf(k[t], q[t], c);
  return __fsub_rn(__fadd_rn(k2, q2), __fmul_rn(2.0f, c));
}

__device__ __forceinline__ unsigned bf2pack(float a, float b) {
  __hip_bfloat16 ha = __float2bfloat16(a), hb = __float2bfloat16(b);
  unsigned short ua = *reinterpret_cast<unsigned short*>(&ha);
  unsigned short ub = *reinterpret_cast<unsigned short*>(&hb);
  return (unsigned)ua | ((unsigned)ub << 16);
}

// Directed bf16 rounding (toward -inf / +inf); exact negation is ^0x8000.
__device__ __forceinline__ unsigned short bf_down(float x) {
  unsigned u = __float_as_uint(x);
  unsigned short hs = (unsigned short)(u >> 16);
  if ((u & 0xFFFFu) && x < 0.0f) hs += 1;
  return hs;
}
__device__ __forceinline__ unsigned short bf_up(float x) {
  unsigned u = __float_as_uint(x);
  unsigned short hs = (unsigned short)(u >> 16);
  if ((u & 0xFFFFu) && x > 0.0f) hs += 1;
  return hs;
}
__device__ __forceinline__ float bf_val(unsigned short h) {
  return __uint_as_float(((unsigned)h) << 16);
}

// ---------------------------------------------------------------------------
// Kernel A: np-exact row norms + bf16 conversion + sqrt norms + query-side
// threshold-ext fragment QE = [1, up(sq), h_hi, h_lo, 0..] with
// h_hi+h_lo <= h = 0.5*q2 (directed: safe).
// ---------------------------------------------------------------------------
__global__ __launch_bounds__(256) void knn_norms_np(
    const float* __restrict__ keys, const float* __restrict__ queries,
    int Nk, int Nq, float* __restrict__ k2, float* __restrict__ q2,
    float* __restrict__ sk, float* __restrict__ sq,
    unsigned short* __restrict__ kbf, unsigned short* __restrict__ qbf,
    unsigned short* __restrict__ QE8) {
  int i = blockIdx.x * 256 + threadIdx.x;
  if (i >= Nk + Nq) return;
  bool isK = i < Nk;
  int r = isK ? i : i - Nk;
  const float4* row4 = reinterpret_cast<const float4*>(
      (isK ? keys : queries) + (size_t)r * DDIM);
  float p[DDIM]; unsigned hw[DDIM / 2];
#pragma unroll
  for (int t = 0; t < 16; ++t) {
    float4 v = row4[t];
    p[4 * t + 0] = __fmul_rn(v.x, v.x);
    p[4 * t + 1] = __fmul_rn(v.y, v.y);
    p[4 * t + 2] = __fmul_rn(v.z, v.z);
    p[4 * t + 3] = __fmul_rn(v.w, v.w);
    hw[2 * t + 0] = bf2pack(v.x, v.y);
    hw[2 * t + 1] = bf2pack(v.z, v.w);
  }
  float s = np_sum64(p);
  uint4* dst = reinterpret_cast<uint4*>((isK ? kbf : qbf) + (size_t)r * DDIM);
#pragma unroll
  for (int t = 0; t < 8; ++t)
    dst[t] = make_uint4(hw[4 * t], hw[4 * t + 1], hw[4 * t + 2], hw[4 * t + 3]);
  if (isK) { k2[r] = s; sk[r] = sqrtf(s); }
  else {
    q2[r] = s;
    float sv = sqrtf(s);
    sq[r] = sv;
    float h = 0.5f * s;
    unsigned short hhi = bf_down(h);            // h > 0: trunc, <= h
    float rem = h - bf_val(hhi);                // >= 0
    unsigned short hlo = (rem > 0.f) ? bf_down(rem) : (unsigned short)0;
    unsigned short e[8] = {0x3F80, bf_up(sv), hhi, hlo, 0, 0, 0, 0};
    uint4* qe = reinterpret_cast<uint4*>(QE8 + (size_t)r * 8);
    *qe = make_uint4((unsigned)e[0] | ((unsigned)e[1] << 16),
                     (unsigned)e[2] | ((unsigned)e[3] << 16), 0u, 0u);
  }
}

// ---------------------------------------------------------------------------
// Kernel B: init cmin = ~0, cnt = cnt2 = 0, spack = ~0 (sentinels).
// ---------------------------------------------------------------------------
__global__ __launch_bounds__(256) void knn_init(
    unsigned* __restrict__ cmin, int nmin,
    unsigned* __restrict__ cnt, unsigned* __restrict__ cnt2, int ncnt,
    unsigned* __restrict__ spw, int nspw) {
  int i = blockIdx.x * 256 + threadIdx.x;
  if (i < nmin) cmin[i] = 0xFFFFFFFFu;
  if (i < ncnt) { cnt[i] = 0u; cnt2[i] = 0u; }
  if (i < nspw) spw[i] = 0xFFFFFFFFu;
}

// ---------------------------------------------------------------------------
// Kernel C (chunkmin): MFMA upper-bound chunk minima over window. Validated r8.
// ---------------------------------------------------------------------------
__global__ __launch_bounds__(256) void knn_chunkmin(
    const unsigned short* __restrict__ kbf, const unsigned short* __restrict__ qbf,
    const float* __restrict__ k2a, const float* __restrict__ ska,
    const float* __restrict__ q2a, const float* __restrict__ sqa,
    unsigned* __restrict__ cmin) {
  int tid = threadIdx.x, lane = tid & 63, w = tid >> 6;
  int kb = blockIdx.x & 127;
  int qt = blockIdx.x >> 7;              // 0..15
  int kbase = kb * 64;
  int qbase = qt * 256 + w * 64;
  int chunk = qbase >> 7;                // 0..31
  int l16 = lane & 15, lg = lane >> 4;

  short8 a0[4], a1[4];
#pragma unroll
  for (int s = 0; s < 4; ++s) {
    const short8* krow = reinterpret_cast<const short8*>(
        kbf + (size_t)(kbase + s * 16 + l16) * DDIM);
    a0[s] = krow[lg]; a1[s] = krow[lg + 4];
  }
  float KA[16], KB[16];
#pragma unroll
  for (int s = 0; s < 4; ++s)
#pragma unroll
    for (int r = 0; r < 4; ++r) {
      int kk = kbase + s * 16 + lg * 4 + r;
      KA[s * 4 + r] = k2a[kk] + C2;
      KB[s * 4 + r] = C1 * ska[kk];
    }
  float mreg[16];
#pragma unroll
  for (int i = 0; i < 16; ++i) mreg[i] = FLT_MAX;

#pragma unroll
  for (int qs = 0; qs < 4; ++qs) {
    int q = qbase + qs * 16 + l16;
    const short8* qrow = reinterpret_cast<const short8*>(qbf + (size_t)q * DDIM);
    short8 b0 = qrow[lg], b1 = qrow[lg + 4];
    float q2l = q2a[q], sql = sqa[q];
    f32x4 acc[4];
#pragma unroll
    for (int s = 0; s < 4; ++s) {
      f32x4 z = {0.f, 0.f, 0.f, 0.f};
      z = __builtin_amdgcn_mfma_f32_16x16x32_bf16(a0[s], b0, z, 0, 0, 0);
      z = __builtin_amdgcn_mfma_f32_16x16x32_bf16(a1[s], b1, z, 0, 0, 0);
      acc[s] = z;
    }
#pragma unroll
    for (int s = 0; s < 4; ++s)
#pragma unroll
      for (int r = 0; r < 4; ++r) {
        int i = s * 4 + r;
        float u = fmaf(KB[i], sql, KA[i] + q2l) - 2.0f * acc[s][r];
        mreg[i] = fminf(mreg[i], u);
      }
  }
#pragma unroll
  for (int m = 1; m < 16; m <<= 1)
#pragma unroll
    for (int i = 0; i < 16; ++i)
      mreg[i] = fminf(mreg[i], __shfl_xor(mreg[i], m));
  if (l16 == 0) {
#pragma unroll
    for (int i = 0; i < 16; ++i) {
      int kk = kbase + (i >> 2) * 16 + lg * 4 + (i & 3);
      atomicMin(&cmin[(size_t)kk * NCHUNK + chunk], mapmono(mreg[i]));
    }
  }
}

// ---------------------------------------------------------------------------
// Kernel D (trough): T_rough[key] = max over 32 chunk minima. Validated r8.
// ---------------------------------------------------------------------------
__global__ __launch_bounds__(256) void knn_trough(
    const unsigned* __restrict__ cmin, float* __restrict__ PR, int Nk) {
  int k = blockIdx.x * 256 + threadIdx.x;
  if (k >= Nk) return;
  unsigned m = 0;
#pragma unroll
  for (int c = 0; c < NCHUNK; ++c) {
    unsigned v = cmin[(size_t)k * NCHUNK + c];
    m = v > m ? v : m;
  }
  PR[k] = unmapmono(m);
}

// ---------------------------------------------------------------------------
// Kernel E (minifilter): MFMA over keys x window; append (u, q) packs where
// u <= T_rough (chunkmin's bitwise expression). Drops only loosen T. r17-
// validated.
// ---------------------------------------------------------------------------
__global__ __launch_bounds__(256) void knn_minifilt(
    const unsigned short* __restrict__ kbf, const unsigned short* __restrict__ qbf,
    const float* __restrict__ k2a, const float* __restrict__ ska,
    const float* __restrict__ q2a, const float* __restrict__ sqa,
    const float* __restrict__ PR,
    unsigned* __restrict__ cnt2, unsigned long long* __restrict__ spack) {
  __shared__ int lcnt[64];
  __shared__ int lbase[64];
  __shared__ unsigned long long lhit[64 * MSLOT];   // 48 KB
  int tid = threadIdx.x;
  int lane = tid & 63, w = tid >> 6;
  int kb = blockIdx.x & 127;
  int qt = blockIdx.x >> 7;              // 0..3
  int kbase = kb * 64;
  int qwave = qt * 1024 + w * 256;
  int l16 = lane & 15, lg = lane >> 4;

  if (tid < 64) lcnt[tid] = 0;
  __syncthreads();

  short8 a0[4], a1[4];
#pragma unroll
  for (int s = 0; s < 4; ++s) {
    const short8* krow = reinterpret_cast<const short8*>(
        kbf + (size_t)(kbase + s * 16 + l16) * DDIM);
    a0[s] = krow[lg]; a1[s] = krow[lg + 4];
  }
  float KA[16], KB[16], PRl[16];
#pragma unroll
  for (int s = 0; s < 4; ++s)
#pragma unroll
    for (int r = 0; r < 4; ++r) {
      int kk = kbase + s * 16 + lg * 4 + r;
      KA[s * 4 + r] = k2a[kk] + C2;
      KB[s * 4 + r] = C1 * ska[kk];
      PRl[s * 4 + r] = PR[kk];
    }

  for (int qo = 0; qo < 4; ++qo) {
    int qbase = qwave + qo * 64;
#pragma unroll
    for (int qs = 0; qs < 4; ++qs) {
      int q = qbase + qs * 16 + l16;
      const short8* qrow = reinterpret_cast<const short8*>(qbf + (size_t)q * DDIM);
      short8 b0 = qrow[lg], b1 = qrow[lg + 4];
      float q2l = q2a[q], sql = sqa[q];

      f32x4 acc[4];
#pragma unroll
      for (int s = 0; s < 4; ++s) {
        f32x4 z = {0.f, 0.f, 0.f, 0.f};
        z = __builtin_amdgcn_mfma_f32_16x16x32_bf16(a0[s], b0, z, 0, 0, 0);
        z = __builtin_amdgcn_mfma_f32_16x16x32_bf16(a1[s], b1, z, 0, 0, 0);
        acc[s] = z;
      }
#pragma unroll
      for (int s = 0; s < 4; ++s)
#pragma unroll
        for (int r = 0; r < 4; ++r) {
          int i = s * 4 + r;
          float u = fmaf(KB[i], sql, KA[i] + q2l) - 2.0f * acc[s][r];
          if (u <= PRl[i]) {
            int kl = s * 16 + lg * 4 + r;
            int slot = atomicAdd(&lcnt[kl], 1);
            if (slot < MSLOT) lhit[kl * MSLOT + slot] = packdj(u, q);
          }
        }
    }
  }
  __syncthreads();
  if (tid < 64) {
    int lc = lcnt[tid];
    int kept = lc < MSLOT ? lc : MSLOT;
    lbase[tid] = (kept > 0) ? (int)atomicAdd(&cnt2[kbase + tid], (unsigned)kept) : 0;
    lcnt[tid] = kept;
  }
  __syncthreads();
  for (int idx = tid; idx < 64 * MSLOT; idx += 256) {
    int kl = idx / MSLOT, sl = idx - kl * MSLOT;
    if (sl < lcnt[kl]) {
      int pos = lbase[kl] + sl;
      if (pos < CAP2)
        spack[(size_t)(kbase + kl) * CAP2 + pos] = lhit[kl * MSLOT + sl];
    }
  }
}

// ---------------------------------------------------------------------------
// Kernel F (thresh2): wave-per-key rank-count over CAP2 slots -> T ->
// key-side threshold-ext fragment KE = [-dn(psA), -dn(psB), -1, -1, 0..]
// (directed rounding: encoded thr' <= thr -> filter pass set is a superset).
// ---------------------------------------------------------------------------
__global__ __launch_bounds__(256) void knn_thresh2(
    const unsigned long long* __restrict__ spack, const float* __restrict__ PR,
    const float* __restrict__ k2a, const float* __restrict__ ska,
    unsigned short* __restrict__ KE8) {
  __shared__ unsigned long long packs[4][CAP2];
  __shared__ float Tsh[4];
  int tid = threadIdx.x, w = tid >> 6, lane = tid & 63;
  int key = blockIdx.x * 4 + w;

  unsigned long long mine[4];
#pragma unroll
  for (int r = 0; r < 4; ++r) {
    int e = lane + 64 * r;
    mine[r] = spack[(size_t)key * CAP2 + e];
    packs[w][e] = mine[r];
  }
  if (lane == 0) Tsh[w] = PR[key];
  __syncthreads();
  int c0 = 0, c1 = 0, c2 = 0, c3 = 0;
  for (int m = 0; m < CAP2; ++m) {
    unsigned long long pm = packs[w][m];
    c0 += pm < mine[0]; c1 += pm < mine[1];
    c2 += pm < mine[2]; c3 += pm < mine[3];
  }
  int c[4] = {c0, c1, c2, c3};
  __syncthreads();
#pragma unroll
  for (int r = 0; r < 4; ++r)
    if (c[r] == KSEL - 1 && mine[r] != ~0ull)
      Tsh[w] = unmapmono((unsigned)(mine[r] >> 32));
  __syncthreads();
  if (lane == 0) {
    float T = Tsh[w];
    float psA = 0.5f * (k2a[key] - T - C2);
    float psB = -0.5f * C1 * ska[key];
    unsigned short e0 = (unsigned short)(bf_down(psA) ^ 0x8000);
    unsigned short e1 = (unsigned short)(bf_down(psB) ^ 0x8000);
    uint4* ke = reinterpret_cast<uint4*>(KE8 + (size_t)key * 8);
    *ke = make_uint4((unsigned)e0 | ((unsigned)e1 << 16),
                     0xBF80u | (0xBF80u << 16), 0u, 0u);
  }
}

// ---------------------------------------------------------------------------
// Kernel G (MFMA filter v6): threshold folded into a third K=32 MFMA via the
// KE/QE ext fragments; epilogue is a bare sign test (acc > 0). Structure
// (4 waves x 64 keys x 1024 q, LDS aggregation, one global atomic per
// (key,block)) proven r13-r17.
// ---------------------------------------------------------------------------
__global__ __launch_bounds__(256) void knn_filter(
    const unsigned short* __restrict__ kbf, const unsigned short* __restrict__ qbf,
    const unsigned short* __restrict__ KE8, const unsigned short* __restrict__ QE8,
    unsigned* __restrict__ cnt, unsigned short* __restrict__ cbuf, int CAP) {
  __shared__ int lcnt[64];
  __shared__ int lbase[64];
  __shared__ unsigned short lhit[64 * LSLOT];
  int tid = threadIdx.x;
  int lane = tid & 63, w = tid >> 6;
  int kb = blockIdx.x & 127;
  int qt = blockIdx.x >> 7;
  int kbase = kb * 64;
  int qwave = qt * 1024 + w * 256;
  int l16 = lane & 15, lg = lane >> 4;
  const short8 z8 = {0, 0, 0, 0, 0, 0, 0, 0};

  if (tid < 64) lcnt[tid] = 0;
  __syncthreads();

  short8 a0[4], a1[4], a2[4];
#pragma unroll
  for (int s = 0; s < 4; ++s) {
    const short8* krow = reinterpret_cast<const short8*>(
        kbf + (size_t)(kbase + s * 16 + l16) * DDIM);
    a0[s] = krow[lg]; a1[s] = krow[lg + 4];
    a2[s] = (lg == 0)
        ? *reinterpret_cast<const short8*>(KE8 + (size_t)(kbase + s * 16 + l16) * 8)
        : z8;
  }

  for (int qo = 0; qo < 4; ++qo) {
    int qbase = qwave + qo * 64;
#pragma unroll
    for (int qs = 0; qs < 4; ++qs) {
      int q = qbase + qs * 16 + l16;
      const short8* qrow = reinterpret_cast<const short8*>(qbf + (size_t)q * DDIM);
      short8 b0 = qrow[lg], b1 = qrow[lg + 4];
      short8 b2 = (lg == 0)
          ? *reinterpret_cast<const short8*>(QE8 + (size_t)q * 8)
          : z8;

      f32x4 acc[4];
#pragma unroll
      for (int s = 0; s < 4; ++s) {
        f32x4 z = {0.f, 0.f, 0.f, 0.f};
        z = __builtin_amdgcn_mfma_f32_16x16x32_bf16(a0[s], b0, z, 0, 0, 0);
        z = __builtin_amdgcn_mfma_f32_16x16x32_bf16(a1[s], b1, z, 0, 0, 0);
        z = __builtin_amdgcn_mfma_f32_16x16x32_bf16(a2[s], b2, z, 0, 0, 0);
        acc[s] = z;
      }
      unsigned m = 0;
#pragma unroll
      for (int s = 0; s < 4; ++s)
#pragma unroll
        for (int r = 0; r < 4; ++r)
          m |= (acc[s][r] > 0.0f) ? (1u << (s * 4 + r)) : 0u;
      while (m) {
        int b = __ffs(m) - 1; m &= m - 1;
        int kl = (b >> 2) * 16 + lg * 4 + (b & 3);
        int slot = atomicAdd(&lcnt[kl], 1);
        if (slot < LSLOT) lhit[kl * LSLOT + slot] = (unsigned short)q;
      }
    }
  }
  __syncthreads();
  if (tid < 64) {
    int lc = lcnt[tid];
    int key = kbase + tid;
    unsigned add = (lc > LSLOT) ? (unsigned)(CAP + 1000) : (unsigned)lc;
    lbase[tid] = (lc > 0) ? (int)atomicAdd(&cnt[key], add) : 0;
    lcnt[tid] = lc < LSLOT ? lc : LSLOT;
  }
  __syncthreads();
  for (int idx = tid; idx < 64 * LSLOT; idx += 256) {
    int kl = idx >> 5, sl = idx & (LSLOT - 1);
    if (sl < lcnt[kl]) {
      int pos = lbase[kl] + sl;
      if (pos < CAP)
        cbuf[(size_t)(kbase + kl) * CAP + pos] = lhit[kl * LSLOT + sl];
    }
  }
}

// ---------------------------------------------------------------------------
// Kernel H (recheck v6, r14/r16/r17-proven): block-per-key, 4 lanes per
// candidate with bit-exact segment-handoff chain. Rank-count selection;
// chunked full-scan fallback.
// ---------------------------------------------------------------------------
__global__ __launch_bounds__(256) void knn_recheck(
    const float* __restrict__ keys, const float* __restrict__ queries,
    const float* __restrict__ k2a, const float* __restrict__ q2a,
    const unsigned* __restrict__ cnt, const unsigned short* __restrict__ cbuf,
    int CAP, int Nq, float* __restrict__ outIdx) {
  __shared__ unsigned long long packs[RBUF];       // 8.3 KB
  __shared__ unsigned long long cur16[KSEL];
  __shared__ float4 klds[16];
  int tid = threadIdx.x;
  int key = blockIdx.x;
  float myk2 = k2a[key];

  if (tid < 16)
    klds[tid] = reinterpret_cast<const float4*>(keys + (size_t)key * DDIM)[tid];
  __syncthreads();

  unsigned n = cnt[key];
  unsigned lim = (unsigned)((CAP < RFAST) ? CAP : RFAST);
  if (n <= lim) {
    const unsigned short* mc = cbuf + (size_t)key * CAP;
    int sub = tid & 3;
    int lanebase = (tid & 63) & ~3;
    for (unsigned base = 0; base < n; base += 64) {
      unsigned e = base + (unsigned)(tid >> 2);
      unsigned ec = (e < n) ? e : (n - 1);
      int j = mc[ec];
      const float4* Q = reinterpret_cast<const float4*>(queries + (size_t)j * DDIM);
      float4 rr[4];
      rr[0] = Q[sub];
      rr[1] = Q[sub + 4];
      rr[2] = Q[sub + 8];
      rr[3] = Q[sub + 12];
      float q2j = q2a[j];
      float c = 0.f;
#pragma unroll
      for (int seg = 0; seg < 16; ++seg) {
        float4 kk = klds[seg];
        float4 qq = rr[seg >> 2];
        float t = c;
        t = fmaf(kk.x, qq.x, t);
        t = fmaf(kk.y, qq.y, t);
        t = fmaf(kk.z, qq.z, t);
        t = fmaf(kk.w, qq.w, t);
        c = __shfl(t, lanebase + (seg & 3), 64);
      }
      if (e < n && sub == 0) {
        float d2 = __fsub_rn(__fadd_rn(myk2, q2j), __fmul_rn(2.0f, c));
        packs[e] = packdj(d2, j);
      }
    }
    __syncthreads();
    int N = (int)n;
    for (int i = tid; i < N; i += 256) {
      unsigned long long mp = packs[i];
      int c = 0;
      for (int m = 0; m < N; ++m) c += packs[m] < mp;
      if (c < KSEL)
        outIdx[(size_t)key * KSEL + c] = (float)(int)(mp & 0xFFFFFFFFull);
    }
    return;
  }

  // ---- fallback: exact full scan (correctness net, expected never) ----
  float bd[KSEL]; int bi[KSEL];
#pragma unroll
  for (int p = 0; p < KSEL; ++p) { bd[p] = FLT_MAX; bi[p] = INT_MAX; }
  const float* krow = keys + (size_t)key * DDIM;
  for (int j = tid; j < Nq; j += 256) {
    float d2 = exact_d2(krow, queries + (size_t)j * DDIM, myk2, q2a[j]);
    if (d2 < bd[KSEL - 1] || (d2 == bd[KSEL - 1] && j < bi[KSEL - 1]))
      insert16(bd, bi, d2, j);
  }
  if (tid < KSEL) cur16[tid] = ~0ull;
  __syncthreads();
  for (int r = 0; r < 4; ++r) {
    if ((tid >> 6) == r) {
#pragma unroll
      for (int p = 0; p < KSEL; ++p)
        packs[KSEL + (tid & 63) * KSEL + p] = packdj(bd[p], bi[p]);
    }
    if (tid < KSEL) packs[tid] = cur16[tid];
    __syncthreads();
    const int N = KSEL + 64 * KSEL;   // 1040
    for (int i = tid; i < N; i += 256) {
      unsigned long long mp = packs[i];
      int c = 0;
      for (int m = 0; m < N; ++m) c += packs[m] < mp;
      if (c < KSEL) cur16[c] = mp;
    }
    __syncthreads();
  }
  if (tid < KSEL)
    outIdx[(size_t)key * KSEL + tid] =
        (float)(int)(cur16[tid] & 0xFFFFFFFFull);
}

// ---------------------------------------------------------------------------
// Kernel I: recompute distances sum((k-q)^2) in f64, emit f32 (validated).
// ---------------------------------------------------------------------------
__global__ __launch_bounds__(256) void knn_dist_d(
    const float* __restrict__ keys, const float* __restrict__ queries,
    const float* __restrict__ outIdx, int Nk, float* __restrict__ outDist) {
  int e = blockIdx.x * 256 + threadIdx.x;
  if (e >= Nk * KSEL) return;
  int key = e >> 4;
  int id = (int)outIdx[e];
  const float* kp = keys + (size_t)key * DDIM;
  const float* qp = queries + (size_t)id * DDIM;
  double s = 0.0;
#pragma unroll
  for (int t = 0; t < DDIM; ++t) {
    double d = (double)kp[t] - (double)qp[t];
    s = fma(d, d, s);
  }
  outDist[e] = (float)s;
}

// ---------------------------------------------------------------------------
extern "C" void kernel_launch(void* const* d_in, const int* in_sizes, int n_in,
                              void* d_out, int out_size, void* d_ws, size_t ws_size,
                              hipStream_t stream) {
  const float* keys    = (const float*)d_in[0];
  const float* queries = (const float*)d_in[1];
  int Nk = in_sizes[0] / DDIM;   // 8192
  int Nq = in_sizes[1] / DDIM;   // 32768
  float* out = (float*)d_out;

  char* wp = (char*)d_ws;
  unsigned long long* spack = (unsigned long long*)wp;
  wp += (size_t)Nk * CAP2 * 8;                             // 16.78 MB
  float*    k2  = (float*)wp;  wp += (size_t)Nk * 4;
  float*    q2  = (float*)wp;  wp += (size_t)Nq * 4;
  float*    sk  = (float*)wp;  wp += (size_t)Nk * 4;
  float*    sq  = (float*)wp;  wp += (size_t)Nq * 4;
  float*    PR  = (float*)wp;  wp += (size_t)Nk * 4;
  unsigned* cnt = (unsigned*)wp; wp += (size_t)Nk * 4;
  unsigned* cnt2 = (unsigned*)wp; wp += (size_t)Nk * 4;
  unsigned* cmin = (unsigned*)wp; wp += (size_t)Nk * NCHUNK * 4;
  unsigned short* kbf = (unsigned short*)wp; wp += (size_t)Nk * DDIM * 2;
  unsigned short* qbf = (unsigned short*)wp; wp += (size_t)Nq * DDIM * 2;
  unsigned short* KE8 = (unsigned short*)wp; wp += (size_t)Nk * 8 * 2;
  unsigned short* QE8 = (unsigned short*)wp; wp += (size_t)Nq * 8 * 2;
  size_t fixedBytes = (size_t)(wp - (char*)d_ws);
  unsigned short* cbuf = (unsigned short*)wp;
  long long rem = (long long)ws_size - (long long)fixedBytes;
  int CAP = (int)(rem / (2 * (long long)Nk));
  if (CAP > 2048) CAP = 2048;
  if (CAP < 16) CAP = 16;

  int nmin = Nk * NCHUNK;                 // 262144
  int nspw = Nk * CAP2 * 2;               // 4,194,304 u32 words
  knn_init<<<(nspw + 255) / 256, 256, 0, stream>>>(
      cmin, nmin, cnt, cnt2, Nk, (unsigned*)spack, nspw);
  knn_norms_np<<<(Nk + Nq + 255) / 256, 256, 0, stream>>>(
      keys, queries, Nk, Nq, k2, q2, sk, sq, kbf, qbf, QE8);
  knn_chunkmin<<<128 * (WINDOW / 256), 256, 0, stream>>>(
      kbf, qbf, k2, sk, q2, sq, cmin);
  knn_trough<<<(Nk + 255) / 256, 256, 0, stream>>>(cmin, PR, Nk);
  knn_minifilt<<<128 * (WINDOW / 1024), 256, 0, stream>>>(
      kbf, qbf, k2, sk, q2, sq, PR, cnt2, spack);
  knn_thresh2<<<Nk / 4, 256, 0, stream>>>(spack, PR, k2, sk, KE8);
  knn_filter<<<128 * (Nq / 1024), 256, 0, stream>>>(
      kbf, qbf, KE8, QE8, cnt, cbuf, CAP);
  knn_recheck<<<Nk, 256, 0, stream>>>(
      keys, queries, k2, q2, cnt, cbuf, CAP, Nq, out);
  knn_dist_d<<<(Nk * KSEL + 255) / 256, 256, 0, stream>>>(
      keys, queries, out, Nk, out + (size_t)Nk * KSEL);
}